// Round 10
// baseline (544.190 us; speedup 1.0000x reference)
//
#include <hip/hip_runtime.h>
#include <stdint.h>

// GMN/EGNN layer: N=50000 nodes, E=800000 edges, F_IN=HID=64, RADIAL=16.
// R10: edge-kernel latency round (others unchanged from R9 / 463 us):
//  - rs_pack software-pipelined one tile ahead (removes a serial vmcnt stall).
//  - segmented row-reduction uses a wave-uniform ballot boundary mask
//    (uniform s_branch flushes instead of 16 shfl+divergent blocks).
//  - radial A-frag built by 4 shfls instead of an LDS round-trip
//    (LDS 35.3 -> 31.0 KB -> 5 blocks/CU); edge grid 1024 -> 1280.

__device__ __forceinline__ uint32_t bf16round(float x) {
    uint32_t u = __float_as_uint(x);
    return (u + 0x7fffu + ((u >> 16) & 1u)) >> 16;
}
__device__ __forceinline__ uint32_t packbf(float a, float b) {
    return bf16round(a) | (bf16round(b) << 16);
}
__device__ __forceinline__ float bflo(uint32_t u) { return __uint_as_float(u << 16); }
__device__ __forceinline__ float bfhi(uint32_t u) { return __uint_as_float(u & 0xffff0000u); }
__device__ __forceinline__ float bfu(ushort u) { return __uint_as_float(((uint32_t)u) << 16); }

typedef __attribute__((ext_vector_type(8))) short short8;
typedef __attribute__((ext_vector_type(4))) float f32x4;

__device__ __forceinline__ int wave_incl_scan(int x) {
    int lane = threadIdx.x & 63;
    #pragma unroll
    for (int off = 1; off < 64; off <<= 1) {
        int y = __shfl_up(x, off, 64);
        if (lane >= off) x += y;
    }
    return x;
}

// ---------------- hist + rank ----------------------------------------------
__global__ __launch_bounds__(256) void hist_rank(
    const int* __restrict__ row, const int* __restrict__ col,
    int* __restrict__ cntR, int* __restrict__ cntC,
    int* __restrict__ rank_r, int* __restrict__ rank_c, int E)
{
    int i = blockIdx.x * blockDim.x + threadIdx.x;
    int stride = gridDim.x * blockDim.x;
    for (; i < E; i += stride) {
        rank_r[i] = atomicAdd(&cntR[row[i]], 1);
        rank_c[i] = atomicAdd(&cntC[col[i]], 1);
    }
}

// ---------------- hierarchical exclusive scan ------------------------------
__global__ __launch_bounds__(1024) void scan_block(
    const int* __restrict__ srcR, const int* __restrict__ srcC,
    int* __restrict__ dstR, int* __restrict__ dstC,
    int* __restrict__ bsumR, int* __restrict__ bsumC, int N)
{
    const int* src = blockIdx.y ? srcC : srcR;
    int* dst  = blockIdx.y ? dstC : dstR;
    int* bsum = blockIdx.y ? bsumC : bsumR;
    __shared__ int s[17];
    int tid = threadIdx.x, lane = tid & 63, wid = tid >> 6;
    int i = blockIdx.x * 1024 + tid;
    int x = (i < N) ? src[i] : 0;
    int incl = wave_incl_scan(x);
    if (lane == 63) s[wid] = incl;
    __syncthreads();
    if (wid == 0) {
        int t = (lane < 16) ? s[lane] : 0;
        int sc = t;
        #pragma unroll
        for (int off = 1; off < 16; off <<= 1) {
            int y = __shfl_up(sc, off, 64);
            if (lane >= off) sc += y;
        }
        if (lane < 16) s[lane] = sc - t;
        if (lane == 15) s[16] = sc;
    }
    __syncthreads();
    if (i < N) dst[i] = s[wid] + incl - x;
    if (tid == 0) bsum[blockIdx.x] = s[16];
}

__global__ __launch_bounds__(64) void scan_totals(
    int* __restrict__ bsumR, int* __restrict__ bsumC,
    int* __restrict__ dstR, int* __restrict__ dstC, int nblk, int N)
{
    int lane = threadIdx.x;
    for (int which = 0; which < 2; which++) {
        int* bs = which ? bsumC : bsumR;
        int* dst = which ? dstC : dstR;
        int running = 0;
        for (int base = 0; base < nblk; base += 64) {
            int idx = base + lane;
            int x = (idx < nblk) ? bs[idx] : 0;
            int incl = wave_incl_scan(x);
            if (idx < nblk) bs[idx] = running + incl - x;   // exclusive offsets
            running += __shfl(incl, 63, 64);
        }
        if (lane == 0) dst[N] = running;                     // grand total
    }
}

__global__ __launch_bounds__(1024) void scan_add(
    int* __restrict__ dstR, int* __restrict__ dstC,
    const int* __restrict__ bsumR, const int* __restrict__ bsumC, int N)
{
    int* dst = blockIdx.y ? dstC : dstR;
    const int* bsum = blockIdx.y ? bsumC : bsumR;
    int i = blockIdx.x * 1024 + threadIdx.x;
    if (i < N) dst[i] += bsum[blockIdx.x];
}

// ---------------- perm build: packed uint4 scatter into row-sorted order ----
__global__ __launch_bounds__(256) void perm_build(
    const int* __restrict__ row, const int* __restrict__ col,
    const int* __restrict__ rowptr, const int* __restrict__ colptr,
    const int* __restrict__ rank_r, const int* __restrict__ rank_c,
    uint4* __restrict__ rs_pack, int E)
{
    int i = blockIdx.x * blockDim.x + threadIdx.x;
    int stride = gridDim.x * blockDim.x;
    for (; i < E; i += stride) {
        int r = row[i], c = col[i];
        int pr = rowptr[r] + rank_r[i];
        int pc = colptr[c] + rank_c[i];
        rs_pack[pr] = make_uint4((uint32_t)r, (uint32_t)c, (uint32_t)pc, 0u);
    }
}

// ---------------- precompute: Xrow/Xcol + hbf ------------------------------
__global__ __launch_bounds__(256) void precompute_xrowcol(
    const float* __restrict__ h, const float* __restrict__ We1,
    const float* __restrict__ be1,
    ushort* __restrict__ Xrow, ushort* __restrict__ Xcol,
    ushort* __restrict__ hbf, int N)
{
    __shared__ uint32_t sWa[32 * 64];
    __shared__ uint32_t sWb[32 * 64];
    __shared__ float sbe1[64];
    int tid = threadIdx.x;
    for (int idx = tid; idx < 32 * 64; idx += 256) {
        int p = idx >> 6, o = idx & 63;
        sWa[idx] = packbf(We1[(2 * p) * 64 + o],      We1[(2 * p + 1) * 64 + o]);
        sWb[idx] = packbf(We1[(64 + 2 * p) * 64 + o], We1[(64 + 2 * p + 1) * 64 + o]);
    }
    if (tid < 64) sbe1[tid] = be1[tid];
    __syncthreads();

    int lane = tid & 63;
    int wv = blockIdx.x * 4 + (tid >> 6);
    int nw = gridDim.x * 4;
    for (int n0 = wv; n0 < N; n0 += nw) {
        int n = __builtin_amdgcn_readfirstlane(n0);
        const float* hn = h + (size_t)n * 64;
        float acc1 = sbe1[lane], acc2 = 0.f;
        #pragma unroll 8
        for (int p = 0; p < 32; p++) {
            float a0 = hn[2 * p], a1 = hn[2 * p + 1];
            uint32_t wa = sWa[p * 64 + lane];
            uint32_t wb = sWb[p * 64 + lane];
            acc1 += a0 * bflo(wa) + a1 * bfhi(wa);
            acc2 += a0 * bflo(wb) + a1 * bfhi(wb);
        }
        Xrow[(size_t)n * 64 + lane] = (ushort)bf16round(acc1);
        Xcol[(size_t)n * 64 + lane] = (ushort)bf16round(acc2);
        hbf[(size_t)n * 64 + lane]  = (ushort)bf16round(hn[lane]);
    }
}

// ---------------- edge kernel: row-sorted, pipelined, fused reductions -----
__global__ __launch_bounds__(256) void edge_kernel(
    const float* __restrict__ Z,
    const uint4* __restrict__ rs_pack,
    const ushort* __restrict__ Xrow, const ushort* __restrict__ Xcol,
    const float* __restrict__ We1, const float* __restrict__ We2, const float* __restrict__ be2,
    const float* __restrict__ Wc1, const float* __restrict__ bc1, const float* __restrict__ Wc2,
    ushort* __restrict__ ef_col,
    float* __restrict__ aggF, float* __restrict__ segF, int E)
{
    __shared__ ushort h1T[4][16 * 72];
    __shared__ ushort efT[4][16 * 72];   // Xcol tile before layer2, ef after
    __shared__ ushort xrT[4][16 * 72];   // Xrow tile
    __shared__ float  cdT[4][16 * 12];   // coord_diff per edge
    __shared__ float  phiT[4][16];

    int tid   = threadIdx.x;
    int lane  = tid & 63;
    int wslot = tid >> 6;
    int l16   = lane & 15;
    int quad  = lane >> 4;

    short8 w1r[4], w2f0[4], w2f1[4], w3f0[4], w3f1[4];
    float be2v[4], bc1v[4], wc2v[4];
    #pragma unroll
    for (int nt = 0; nt < 4; nt++) {
        int n = nt * 16 + l16;
        #pragma unroll
        for (int j = 0; j < 8; j++) {
            int k = quad * 8 + j;
            w1r[nt][j]  = (k < 16) ? (short)bf16round(We1[(128 + k) * 64 + n]) : (short)0;
            w2f0[nt][j] = (short)bf16round(We2[k * 64 + n]);
            w2f1[nt][j] = (short)bf16round(We2[(32 + k) * 64 + n]);
            w3f0[nt][j] = (short)bf16round(Wc1[k * 64 + n]);
            w3f1[nt][j] = (short)bf16round(Wc1[(32 + k) * 64 + n]);
        }
        be2v[nt] = be2[n];
        bc1v[nt] = bc1[n];
        wc2v[nt] = Wc2[n];
    }

    int e_l = lane >> 2;
    int cb  = (lane & 3) * 3;

    const f32x4 z4 = {0.f, 0.f, 0.f, 0.f};
    int ntile = (E + 15) >> 4;
    int stride = gridDim.x * 4;
    int t = blockIdx.x * 4 + wslot;

    // prime the pipeline: tile t's indices
    uint4 rsv = make_uint4(0u, 0u, 0u, 0u);
    if (t < ntile) rsv = rs_pack[min(t * 16 + l16, E - 1)];

    for (; t < ntile; t += stride) {
        int e0 = t * 16;
        uint4 rsc = rsv;                       // current tile's indices
        int tn = t + stride;                   // prefetch next tile's indices
        if (tn < ntile) rsv = rs_pack[min(tn * 16 + l16, E - 1)];

        int rowv = (int)rsc.x;
        int colv = (int)rsc.y;
        int pcv  = (int)rsc.z;

        // ---- stage Xrow/Xcol rows into LDS (uint4 loads, 8 lanes/row) ----
        {
            int off = lane & 7, es = lane >> 3;
            #pragma unroll
            for (int i = 0; i < 2; i++) {
                int e = es + i * 8;
                int nr = __shfl(rowv, e, 64);
                int nc = __shfl(colv, e, 64);
                uint4 vr = *(const uint4*)(Xrow + (size_t)nr * 64 + off * 8);
                uint4 vc = *(const uint4*)(Xcol + (size_t)nc * 64 + off * 8);
                *(uint4*)&xrT[wslot][e * 72 + off * 8] = vr;
                *(uint4*)&efT[wslot][e * 72 + off * 8] = vc;
            }
        }

        // ---- coord_diff + gram + radial (4 lanes per edge) ----
        int rZ = __shfl(rowv, e_l, 64);
        int cZ = __shfl(colv, e_l, 64);
        const float* Zr = Z + (size_t)rZ * 12 + cb;
        const float* Zc = Z + (size_t)cZ * 12 + cb;
        float cd0 = Zr[0] - Zc[0];
        float cd1 = Zr[1] - Zc[1];
        float cd2 = Zr[2] - Zc[2];
        cdT[wslot][e_l * 12 + cb + 0] = cd0;
        cdT[wslot][e_l * 12 + cb + 1] = cd1;
        cdT[wslot][e_l * 12 + cb + 2] = cd2;

        int gbase = lane & ~3;
        float g0, g1, g2, g3;
        {
            float a0 = __shfl(cd0, gbase + 0, 64), b0 = __shfl(cd1, gbase + 0, 64), c0 = __shfl(cd2, gbase + 0, 64);
            float a1 = __shfl(cd0, gbase + 1, 64), b1 = __shfl(cd1, gbase + 1, 64), c1 = __shfl(cd2, gbase + 1, 64);
            float a2 = __shfl(cd0, gbase + 2, 64), b2 = __shfl(cd1, gbase + 2, 64), c2 = __shfl(cd2, gbase + 2, 64);
            float a3 = __shfl(cd0, gbase + 3, 64), b3 = __shfl(cd1, gbase + 3, 64), c3 = __shfl(cd2, gbase + 3, 64);
            g0 = cd0 * a0 + cd1 * b0 + cd2 * c0;
            g1 = cd0 * a1 + cd1 * b1 + cd2 * c1;
            g2 = cd0 * a2 + cd1 * b2 + cd2 * c2;
            g3 = cd0 * a3 + cd1 * b3 + cd2 * c3;
        }
        float s = g0 * g0 + g1 * g1 + g2 * g2 + g3 * g3;
        s += __shfl_xor(s, 1, 64);
        s += __shfl_xor(s, 2, 64);
        float inv = 1.f / fmaxf(sqrtf(s), 1e-12f);

        // packed radial on the (e_l, lane&3) layout
        uint32_t rpx = packbf(g0 * inv, g1 * inv);
        uint32_t rpy = packbf(g2 * inv, g3 * inv);

        // ---- build radial A-frag via shfl (no LDS round-trip) ----
        // aR[j] = radial[l16][quad*8+j]; source lane for k is l16*4 + (k>>2)
        short8 aR;
        {
            int s0 = l16 * 4 + quad * 2;       // valid for quad<2
            uint32_t x0 = __shfl(rpx, s0, 64), y0 = __shfl(rpy, s0, 64);
            uint32_t x1 = __shfl(rpx, s0 + 1, 64), y1 = __shfl(rpy, s0 + 1, 64);
            union { short8 v; uint32_t u[4]; } au;
            bool qlo = (quad < 2);
            au.u[0] = qlo ? x0 : 0u;
            au.u[1] = qlo ? y0 : 0u;
            au.u[2] = qlo ? x1 : 0u;
            au.u[3] = qlo ? y1 : 0u;
            aR = au.v;
        }

        // ---- layer 1: radial @ We1[128:144] ----
        f32x4 c1t[4];
        #pragma unroll
        for (int nt = 0; nt < 4; nt++)
            c1t[nt] = __builtin_amdgcn_mfma_f32_16x16x32_bf16(aR, w1r[nt], z4, 0, 0, 0);

        // ---- + Xrow + Xcol (from LDS), relu, write h1 tile ----
        __builtin_amdgcn_wave_barrier();
        #pragma unroll
        for (int nt = 0; nt < 4; nt++) {
            int n = nt * 16 + l16;
            #pragma unroll
            for (int reg = 0; reg < 4; reg++) {
                int eL = quad * 4 + reg;
                float hv = c1t[nt][reg]
                         + bfu(xrT[wslot][eL * 72 + n])
                         + bfu(efT[wslot][eL * 72 + n]);
                hv = fmaxf(hv, 0.f);
                h1T[wslot][eL * 72 + n] = (ushort)bf16round(hv);
            }
        }
        __builtin_amdgcn_wave_barrier();

        // ---- layer 2: h1 @ We2 + be2, relu -> edge_feat (overwrites efT) ----
        short8 a20 = *(const short8*)&h1T[wslot][l16 * 72 + quad * 8];
        short8 a21 = *(const short8*)&h1T[wslot][l16 * 72 + 32 + quad * 8];
        f32x4 c2t[4];
        #pragma unroll
        for (int nt = 0; nt < 4; nt++) {
            f32x4 a = __builtin_amdgcn_mfma_f32_16x16x32_bf16(a20, w2f0[nt], z4, 0, 0, 0);
            c2t[nt]  = __builtin_amdgcn_mfma_f32_16x16x32_bf16(a21, w2f1[nt], a, 0, 0, 0);
        }

        __builtin_amdgcn_wave_barrier();
        #pragma unroll
        for (int nt = 0; nt < 4; nt++) {
            int n = nt * 16 + l16;
            #pragma unroll
            for (int reg = 0; reg < 4; reg++) {
                float ef = fmaxf(c2t[nt][reg] + be2v[nt], 0.f);
                efT[wslot][(quad * 4 + reg) * 72 + n] = (ushort)bf16round(ef);
            }
        }
        __builtin_amdgcn_wave_barrier();

        // ---- ef_col: scatter full rows to col-sorted slots ----
        {
            int off = lane & 7, es = lane >> 3;
            #pragma unroll
            for (int i = 0; i < 2; i++) {
                int e = es + i * 8;
                int pc = __shfl(pcv, e, 64);
                if (e0 + e < E)
                    *(uint4*)(ef_col + (size_t)pc * 64 + off * 8) =
                        *(const uint4*)&efT[wslot][e * 72 + off * 8];
            }
        }

        // ---- layer 3: edge_feat @ Wc1 + bc1, relu, @ Wc2 -> phi ----
        short8 a30 = *(const short8*)&efT[wslot][l16 * 72 + quad * 8];
        short8 a31 = *(const short8*)&efT[wslot][l16 * 72 + 32 + quad * 8];
        float ps[4] = {0.f, 0.f, 0.f, 0.f};
        #pragma unroll
        for (int nt = 0; nt < 4; nt++) {
            f32x4 a = __builtin_amdgcn_mfma_f32_16x16x32_bf16(a30, w3f0[nt], z4, 0, 0, 0);
            f32x4 c = __builtin_amdgcn_mfma_f32_16x16x32_bf16(a31, w3f1[nt], a, 0, 0, 0);
            #pragma unroll
            for (int reg = 0; reg < 4; reg++)
                ps[reg] += fmaxf(c[reg] + bc1v[nt], 0.f) * wc2v[nt];
        }
        #pragma unroll
        for (int reg = 0; reg < 4; reg++) {
            ps[reg] += __shfl_xor(ps[reg], 1, 64);
            ps[reg] += __shfl_xor(ps[reg], 2, 64);
            ps[reg] += __shfl_xor(ps[reg], 4, 64);
            ps[reg] += __shfl_xor(ps[reg], 8, 64);
        }
        __builtin_amdgcn_wave_barrier();
        if (l16 == 0) {
            f32x4 pv = {ps[0], ps[1], ps[2], ps[3]};
            *(f32x4*)&phiT[wslot][quad * 4] = pv;
        }
        __builtin_amdgcn_wave_barrier();

        // ---- in-tile segmented reduction, wave-uniform ballot mask ----
        {
            // run-boundary mask from lanes 0..14 (rowv depends only on l16)
            int rnext = __shfl_down(rowv, 1, 64);
            unsigned long long bl = __ballot(rowv != rnext);
            uint32_t mask = (uint32_t)bl & 0x7FFFu;   // bits 0..14

            float accA = 0.f, accS = 0.f;
            int a = 0;
            #pragma unroll
            for (int e = 0; e < 16; e++) {
                bool valid = (e0 + e) < E;
                float v = valid ? bfu(efT[wslot][e * 72 + lane]) : 0.f;
                accA += v;
                if (lane < 12 && valid)
                    accS += phiT[wslot][e] * cdT[wslot][e * 12 + lane];
                if (e == 15 || ((mask >> e) & 1u)) {   // wave-uniform branch
                    int node = __shfl(rowv, e, 64);
                    bool interior = (a > 0) && (e < 15);
                    if ((e0 + a) < E) {
                        if (interior) {
                            aggF[(size_t)node * 64 + lane] = accA;
                            if (lane < 12) segF[(size_t)node * 12 + lane] = accS;
                        } else {
                            unsafeAtomicAdd(&aggF[(size_t)node * 64 + lane], accA);
                            if (lane < 12) unsafeAtomicAdd(&segF[(size_t)node * 12 + lane], accS);
                        }
                    }
                    a = e + 1;
                    accA = 0.f;
                    accS = 0.f;
                }
            }
        }
        __builtin_amdgcn_wave_barrier();
    }
}

// ---------------- reduce kernel: streaming "others" only (unroll x4) -------
__global__ __launch_bounds__(256) void reduce_kernel(
    const int* __restrict__ colptr, const ushort* __restrict__ ef_col,
    ushort* __restrict__ othersB, int N)
{
    int tid = threadIdx.x;
    int lane = tid & 63, wslot = tid >> 6;
    int wv = blockIdx.x * 4 + wslot, nw = gridDim.x * 4;

    for (int n0 = wv; n0 < N; n0 += nw) {
        int n = __builtin_amdgcn_readfirstlane(n0);
        int cs = colptr[n], ceN = colptr[n + 1];
        float inv_col = 1.f / (float)max(ceN - cs, 1);

        float othv = 0.f;
        int p = cs;
        for (; p + 3 < ceN; p += 4) {
            float a = bfu(ef_col[(size_t)p * 64 + lane]);
            float b = bfu(ef_col[(size_t)(p + 1) * 64 + lane]);
            float c = bfu(ef_col[(size_t)(p + 2) * 64 + lane]);
            float d = bfu(ef_col[(size_t)(p + 3) * 64 + lane]);
            othv += (a + b) + (c + d);
        }
        for (; p < ceN; p++) othv += bfu(ef_col[(size_t)p * 64 + lane]);
        othv *= inv_col;

        othersB[(size_t)n * 64 + lane] = (ushort)bf16round(othv);
    }
}

// ---------------- mlp kernel: 16 nodes per wave, MFMA ----------------------
__global__ __launch_bounds__(256) void mlp_kernel(
    const float* __restrict__ h, const float* __restrict__ Z,
    const ushort* __restrict__ hbf,
    const float* __restrict__ aggF, const ushort* __restrict__ othersB,
    const float* __restrict__ segF, const int* __restrict__ rowptr,
    const float* __restrict__ Wn1, const float* __restrict__ bn1,
    const float* __restrict__ Wn2, const float* __restrict__ bn2,
    const float* __restrict__ Wv1, const float* __restrict__ bv1,
    const float* __restrict__ Wv2, const float* __restrict__ bv2,
    float* __restrict__ out, int N)
{
    __shared__ ushort aT[4][16 * 200];
    __shared__ ushort h1T[4][16 * 72];
    __shared__ float  scT[4][16];
    __shared__ float  irT[4][16];

    int tid   = threadIdx.x;
    int lane  = tid & 63;
    int wslot = tid >> 6;
    int l16   = lane & 15;
    int quad  = lane >> 4;

    short8 wn1f[6][4], wn2f[2][4], wv1f[2][4];
    float bn1v[4], bn2v[4], bv1v[4], wv2v[4];
    #pragma unroll
    for (int nt = 0; nt < 4; nt++) {
        int n = nt * 16 + l16;
        #pragma unroll
        for (int kc = 0; kc < 6; kc++)
            #pragma unroll
            for (int j = 0; j < 8; j++)
                wn1f[kc][nt][j] = (short)bf16round(Wn1[(kc * 32 + quad * 8 + j) * 64 + n]);
        #pragma unroll
        for (int kc = 0; kc < 2; kc++)
            #pragma unroll
            for (int j = 0; j < 8; j++) {
                wn2f[kc][nt][j] = (short)bf16round(Wn2[(kc * 32 + quad * 8 + j) * 64 + n]);
                wv1f[kc][nt][j] = (short)bf16round(Wv1[(kc * 32 + quad * 8 + j) * 64 + n]);
            }
        bn1v[nt] = bn1[n];
        bn2v[nt] = bn2[n];
        bv1v[nt] = bv1[n];
        wv2v[nt] = Wv2[n];
    }
    float bv2s = bv2[0];

    const f32x4 z4 = {0.f, 0.f, 0.f, 0.f};
    size_t OZ = (size_t)N * 64, OX = (size_t)N * 76, OV = (size_t)N * 79;
    int ntile = (N + 15) >> 4;
    for (int t = blockIdx.x * 4 + wslot; t < ntile; t += gridDim.x * 4) {
        int n0 = t * 16;

        // inv_row per node
        if (lane < 16) {
            int node = min(n0 + lane, N - 1);
            irT[wslot][lane] = 1.f / (float)max(rowptr[node + 1] - rowptr[node], 1);
        }

        // ---- stage A tile: [others | h | agg(fp32->bf16)] ----
        {
            #pragma unroll
            for (int i = 0; i < 2; i++) {
                int c = i * 64 + lane;
                int r = c >> 3, off = c & 7;
                int nn = min(n0 + r, N - 1);
                uint4 vo = *(const uint4*)(othersB + (size_t)nn * 64 + off * 8);
                uint4 vh = *(const uint4*)(hbf     + (size_t)nn * 64 + off * 8);
                float4 f0 = *(const float4*)(aggF + (size_t)nn * 64 + off * 8);
                float4 f1 = *(const float4*)(aggF + (size_t)nn * 64 + off * 8 + 4);
                uint4 va = make_uint4(packbf(f0.x, f0.y), packbf(f0.z, f0.w),
                                      packbf(f1.x, f1.y), packbf(f1.z, f1.w));
                *(uint4*)&aT[wslot][r * 200 +       off * 8] = vo;
                *(uint4*)&aT[wslot][r * 200 +  64 + off * 8] = vh;
                *(uint4*)&aT[wslot][r * 200 + 128 + off * 8] = va;
            }
        }
        __builtin_amdgcn_wave_barrier();

        // ---- Z_new = Z + segF/cnt (12 comps per node) ----
        #pragma unroll
        for (int i = 0; i < 4; i++) {
            int nd = i * 4 + (lane >> 4);
            int comp = lane & 15;
            int node = n0 + nd;
            if (comp < 12 && node < N) {
                float f = segF[(size_t)node * 12 + comp] * irT[wslot][nd];
                out[OZ + (size_t)node * 12 + comp] = Z[(size_t)node * 12 + comp] + f;
            }
        }

        // ---- layer 1: A @ Wn1 + bn1, relu ----
        f32x4 c1t[4];
        short8 af[6];
        #pragma unroll
        for (int kc = 0; kc < 6; kc++)
            af[kc] = *(const short8*)&aT[wslot][l16 * 200 + kc * 32 + quad * 8];
        #pragma unroll
        for (int nt = 0; nt < 4; nt++) {
            f32x4 c = z4;
            #pragma unroll
            for (int kc = 0; kc < 6; kc++)
                c = __builtin_amdgcn_mfma_f32_16x16x32_bf16(af[kc], wn1f[kc][nt], c, 0, 0, 0);
            c1t[nt] = c;
        }
        __builtin_amdgcn_wave_barrier();
        #pragma unroll
        for (int nt = 0; nt < 4; nt++) {
            int n = nt * 16 + l16;
            #pragma unroll
            for (int reg = 0; reg < 4; reg++) {
                float hv = fmaxf(c1t[nt][reg] + bn1v[nt], 0.f);
                h1T[wslot][(quad * 4 + reg) * 72 + n] = (ushort)bf16round(hv);
            }
        }
        __builtin_amdgcn_wave_barrier();

        // ---- layer 2: h1 @ Wn2 + bn2; h_new = h + . ----
        short8 a20 = *(const short8*)&h1T[wslot][l16 * 72 + quad * 8];
        short8 a21 = *(const short8*)&h1T[wslot][l16 * 72 + 32 + quad * 8];
        f32x4 hnewT[4];
        #pragma unroll
        for (int nt = 0; nt < 4; nt++) {
            f32x4 a = __builtin_amdgcn_mfma_f32_16x16x32_bf16(a20, wn2f[0][nt], z4, 0, 0, 0);
            f32x4 c = __builtin_amdgcn_mfma_f32_16x16x32_bf16(a21, wn2f[1][nt], a, 0, 0, 0);
            int n = nt * 16 + l16;
            #pragma unroll
            for (int reg = 0; reg < 4; reg++) {
                int node = n0 + quad * 4 + reg;
                int nc = min(node, N - 1);
                float hnew = h[(size_t)nc * 64 + n] + c[reg] + bn2v[nt];
                hnewT[nt][reg] = hnew;
                if (node < N) out[(size_t)node * 64 + n] = hnew;
            }
        }

        // ---- vel mlp ----
        __builtin_amdgcn_wave_barrier();
        #pragma unroll
        for (int nt = 0; nt < 4; nt++) {
            int n = nt * 16 + l16;
            #pragma unroll
            for (int reg = 0; reg < 4; reg++)
                h1T[wslot][(quad * 4 + reg) * 72 + n] = (ushort)bf16round(hnewT[nt][reg]);
        }
        __builtin_amdgcn_wave_barrier();
        short8 a30 = *(const short8*)&h1T[wslot][l16 * 72 + quad * 8];
        short8 a31 = *(const short8*)&h1T[wslot][l16 * 72 + 32 + quad * 8];
        float ps[4] = {0.f, 0.f, 0.f, 0.f};
        #pragma unroll
        for (int nt = 0; nt < 4; nt++) {
            f32x4 a = __builtin_amdgcn_mfma_f32_16x16x32_bf16(a30, wv1f[0][nt], z4, 0, 0, 0);
            f32x4 c = __builtin_amdgcn_mfma_f32_16x16x32_bf16(a31, wv1f[1][nt], a, 0, 0, 0);
            #pragma unroll
            for (int reg = 0; reg < 4; reg++)
                ps[reg] += fmaxf(c[reg] + bv1v[nt], 0.f) * wv2v[nt];
        }
        #pragma unroll
        for (int reg = 0; reg < 4; reg++) {
            ps[reg] += __shfl_xor(ps[reg], 1, 64);
            ps[reg] += __shfl_xor(ps[reg], 2, 64);
            ps[reg] += __shfl_xor(ps[reg], 4, 64);
            ps[reg] += __shfl_xor(ps[reg], 8, 64);
        }
        __builtin_amdgcn_wave_barrier();
        if (l16 == 0) {
            f32x4 pv = {ps[0] + bv2s, ps[1] + bv2s, ps[2] + bv2s, ps[3] + bv2s};
            *(f32x4*)&scT[wslot][quad * 4] = pv;
        }
        __builtin_amdgcn_wave_barrier();

        // ---- x_new / v_new ----
        if (lane < 48) {
            int nd = lane / 3, comp = lane - nd * 3;
            int node = n0 + nd;
            if (node < N) {
                float scale = scT[wslot][nd];
                float f = segF[(size_t)node * 12 + comp] * irT[wslot][nd];
                float v = scale * Z[(size_t)node * 12 + 3 + comp] + f;
                float x = Z[(size_t)node * 12 + comp] + v;
                out[OX + (size_t)node * 3 + comp] = x;
                out[OV + (size_t)node * 3 + comp] = v;
            }
        }
        __builtin_amdgcn_wave_barrier();
    }
}

extern "C" void kernel_launch(void* const* d_in, const int* in_sizes, int n_in,
                              void* d_out, int out_size, void* d_ws, size_t ws_size,
                              hipStream_t stream) {
    const float* h   = (const float*)d_in[0];
    const float* Z   = (const float*)d_in[1];
    const int*   row = (const int*)d_in[2];
    const int*   col = (const int*)d_in[3];
    const float* We1 = (const float*)d_in[4];
    const float* be1 = (const float*)d_in[5];
    const float* We2 = (const float*)d_in[6];
    const float* be2 = (const float*)d_in[7];
    const float* Wn1 = (const float*)d_in[8];
    const float* bn1 = (const float*)d_in[9];
    const float* Wn2 = (const float*)d_in[10];
    const float* bn2 = (const float*)d_in[11];
    const float* Wc1 = (const float*)d_in[12];
    const float* bc1 = (const float*)d_in[13];
    const float* Wc2 = (const float*)d_in[14];
    const float* Wv1 = (const float*)d_in[15];
    const float* bv1 = (const float*)d_in[16];
    const float* Wv2 = (const float*)d_in[17];
    const float* bv2 = (const float*)d_in[18];

    int N = in_sizes[0] / 64;
    int E = in_sizes[2];
    int nblk = (N + 1023) / 1024;

    // workspace layout; zeroed region first (cnt + fp32 accumulators)
    char* ws = (char*)d_ws;
    size_t o = 0;
    int* cntR    = (int*)(ws + o); o += (size_t)N * 4;
    int* cntC    = (int*)(ws + o); o += (size_t)N * 4;
    float* aggF  = (float*)(ws + o); o += (size_t)N * 64 * 4;   // 12.8 MB
    float* segF  = (float*)(ws + o); o += (size_t)N * 12 * 4;   //  2.4 MB
    size_t zero_bytes = o;
    int* rowptr  = (int*)(ws + o); o += (size_t)(N + 1) * 4;
    int* colptr  = (int*)(ws + o); o += (size_t)(N + 1) * 4;
    int* bsumR   = (int*)(ws + o); o += (size_t)nblk * 4;
    int* bsumC   = (int*)(ws + o); o += (size_t)nblk * 4;
    int* rank_r  = (int*)(ws + o); o += (size_t)E * 4;
    int* rank_c  = (int*)(ws + o); o += (size_t)E * 4;
    o = (o + 15) & ~(size_t)15;
    uint4* rs_pack = (uint4*)(ws + o); o += (size_t)E * 16;     // 12.8 MB
    ushort* Xrow = (ushort*)(ws + o); o += (size_t)N * 64 * 2;
    ushort* Xcol = (ushort*)(ws + o); o += (size_t)N * 64 * 2;
    ushort* hbf  = (ushort*)(ws + o); o += (size_t)N * 64 * 2;
    ushort* othersB = (ushort*)(ws + o); o += (size_t)N * 64 * 2;
    ushort* ef_col = (ushort*)(ws + o); o += (size_t)E * 64 * 2;  // 102.4 MB
    float* out = (float*)d_out;

    hipMemsetAsync(d_ws, 0, zero_bytes, stream);
    hist_rank<<<1024, 256, 0, stream>>>(row, col, cntR, cntC, rank_r, rank_c, E);
    scan_block<<<dim3(nblk, 2), 1024, 0, stream>>>(cntR, cntC, rowptr, colptr,
                                                   bsumR, bsumC, N);
    scan_totals<<<1, 64, 0, stream>>>(bsumR, bsumC, rowptr, colptr, nblk, N);
    scan_add<<<dim3(nblk, 2), 1024, 0, stream>>>(rowptr, colptr, bsumR, bsumC, N);
    perm_build<<<1024, 256, 0, stream>>>(row, col, rowptr, colptr,
                                         rank_r, rank_c, rs_pack, E);
    precompute_xrowcol<<<512, 256, 0, stream>>>(h, We1, be1, Xrow, Xcol, hbf, N);
    edge_kernel<<<1280, 256, 0, stream>>>(Z, rs_pack, Xrow, Xcol,
                                          We1, We2, be2, Wc1, bc1, Wc2,
                                          ef_col, aggF, segF, E);
    reduce_kernel<<<2048, 256, 0, stream>>>(colptr, ef_col, othersB, N);
    mlp_kernel<<<800, 256, 0, stream>>>(h, Z, hbf, aggF, othersB, segF, rowptr,
                                        Wn1, bn1, Wn2, bn2, Wv1, bv1, Wv2, bv2,
                                        out, N);
}

// Round 11
// 465.314 us; speedup vs baseline: 1.1695x; 1.1695x over previous
//
#include <hip/hip_runtime.h>
#include <stdint.h>

// GMN/EGNN layer: N=50000 nodes, E=800000 edges, F_IN=HID=64, RADIAL=16.
// R11 = R9 (best, 463us) with index plumbing split: perm scatters uint2(row,col)
// + dword(pc) — edge reads the measured-faster narrow streams (R7 pattern was
// 156us vs R9's uint4 at 178us). R10's prefetch/shfl experiment (occupancy
// halved, VGPR 136) is fully reverted.

__device__ __forceinline__ uint32_t bf16round(float x) {
    uint32_t u = __float_as_uint(x);
    return (u + 0x7fffu + ((u >> 16) & 1u)) >> 16;
}
__device__ __forceinline__ uint32_t packbf(float a, float b) {
    return bf16round(a) | (bf16round(b) << 16);
}
__device__ __forceinline__ float bflo(uint32_t u) { return __uint_as_float(u << 16); }
__device__ __forceinline__ float bfhi(uint32_t u) { return __uint_as_float(u & 0xffff0000u); }
__device__ __forceinline__ float bfu(ushort u) { return __uint_as_float(((uint32_t)u) << 16); }

typedef __attribute__((ext_vector_type(8))) short short8;
typedef __attribute__((ext_vector_type(4))) float f32x4;

__device__ __forceinline__ int wave_incl_scan(int x) {
    int lane = threadIdx.x & 63;
    #pragma unroll
    for (int off = 1; off < 64; off <<= 1) {
        int y = __shfl_up(x, off, 64);
        if (lane >= off) x += y;
    }
    return x;
}

// ---------------- hist + rank ----------------------------------------------
__global__ __launch_bounds__(256) void hist_rank(
    const int* __restrict__ row, const int* __restrict__ col,
    int* __restrict__ cntR, int* __restrict__ cntC,
    int* __restrict__ rank_r, int* __restrict__ rank_c, int E)
{
    int i = blockIdx.x * blockDim.x + threadIdx.x;
    int stride = gridDim.x * blockDim.x;
    for (; i < E; i += stride) {
        rank_r[i] = atomicAdd(&cntR[row[i]], 1);
        rank_c[i] = atomicAdd(&cntC[col[i]], 1);
    }
}

// ---------------- hierarchical exclusive scan ------------------------------
__global__ __launch_bounds__(1024) void scan_block(
    const int* __restrict__ srcR, const int* __restrict__ srcC,
    int* __restrict__ dstR, int* __restrict__ dstC,
    int* __restrict__ bsumR, int* __restrict__ bsumC, int N)
{
    const int* src = blockIdx.y ? srcC : srcR;
    int* dst  = blockIdx.y ? dstC : dstR;
    int* bsum = blockIdx.y ? bsumC : bsumR;
    __shared__ int s[17];
    int tid = threadIdx.x, lane = tid & 63, wid = tid >> 6;
    int i = blockIdx.x * 1024 + tid;
    int x = (i < N) ? src[i] : 0;
    int incl = wave_incl_scan(x);
    if (lane == 63) s[wid] = incl;
    __syncthreads();
    if (wid == 0) {
        int t = (lane < 16) ? s[lane] : 0;
        int sc = t;
        #pragma unroll
        for (int off = 1; off < 16; off <<= 1) {
            int y = __shfl_up(sc, off, 64);
            if (lane >= off) sc += y;
        }
        if (lane < 16) s[lane] = sc - t;
        if (lane == 15) s[16] = sc;
    }
    __syncthreads();
    if (i < N) dst[i] = s[wid] + incl - x;
    if (tid == 0) bsum[blockIdx.x] = s[16];
}

__global__ __launch_bounds__(64) void scan_totals(
    int* __restrict__ bsumR, int* __restrict__ bsumC,
    int* __restrict__ dstR, int* __restrict__ dstC, int nblk, int N)
{
    int lane = threadIdx.x;
    for (int which = 0; which < 2; which++) {
        int* bs = which ? bsumC : bsumR;
        int* dst = which ? dstC : dstR;
        int running = 0;
        for (int base = 0; base < nblk; base += 64) {
            int idx = base + lane;
            int x = (idx < nblk) ? bs[idx] : 0;
            int incl = wave_incl_scan(x);
            if (idx < nblk) bs[idx] = running + incl - x;   // exclusive offsets
            running += __shfl(incl, 63, 64);
        }
        if (lane == 0) dst[N] = running;                     // grand total
    }
}

__global__ __launch_bounds__(1024) void scan_add(
    int* __restrict__ dstR, int* __restrict__ dstC,
    const int* __restrict__ bsumR, const int* __restrict__ bsumC, int N)
{
    int* dst = blockIdx.y ? dstC : dstR;
    const int* bsum = blockIdx.y ? bsumC : bsumR;
    int i = blockIdx.x * 1024 + threadIdx.x;
    if (i < N) dst[i] += bsum[blockIdx.x];
}

// ---------------- perm build: uint2(row,col) + dword(pc) scatter -----------
__global__ __launch_bounds__(256) void perm_build(
    const int* __restrict__ row, const int* __restrict__ col,
    const int* __restrict__ rowptr, const int* __restrict__ colptr,
    const int* __restrict__ rank_r, const int* __restrict__ rank_c,
    uint2* __restrict__ rs_rc, int* __restrict__ rs_pc, int E)
{
    int i = blockIdx.x * blockDim.x + threadIdx.x;
    int stride = gridDim.x * blockDim.x;
    for (; i < E; i += stride) {
        int r = row[i], c = col[i];
        int pr = rowptr[r] + rank_r[i];
        int pc = colptr[c] + rank_c[i];
        rs_rc[pr] = make_uint2((uint32_t)r, (uint32_t)c);
        rs_pc[pr] = pc;
    }
}

// ---------------- precompute: Xrow/Xcol + hbf ------------------------------
__global__ __launch_bounds__(256) void precompute_xrowcol(
    const float* __restrict__ h, const float* __restrict__ We1,
    const float* __restrict__ be1,
    ushort* __restrict__ Xrow, ushort* __restrict__ Xcol,
    ushort* __restrict__ hbf, int N)
{
    __shared__ uint32_t sWa[32 * 64];
    __shared__ uint32_t sWb[32 * 64];
    __shared__ float sbe1[64];
    int tid = threadIdx.x;
    for (int idx = tid; idx < 32 * 64; idx += 256) {
        int p = idx >> 6, o = idx & 63;
        sWa[idx] = packbf(We1[(2 * p) * 64 + o],      We1[(2 * p + 1) * 64 + o]);
        sWb[idx] = packbf(We1[(64 + 2 * p) * 64 + o], We1[(64 + 2 * p + 1) * 64 + o]);
    }
    if (tid < 64) sbe1[tid] = be1[tid];
    __syncthreads();

    int lane = tid & 63;
    int wv = blockIdx.x * 4 + (tid >> 6);
    int nw = gridDim.x * 4;
    for (int n0 = wv; n0 < N; n0 += nw) {
        int n = __builtin_amdgcn_readfirstlane(n0);
        const float* hn = h + (size_t)n * 64;
        float acc1 = sbe1[lane], acc2 = 0.f;
        #pragma unroll 8
        for (int p = 0; p < 32; p++) {
            float a0 = hn[2 * p], a1 = hn[2 * p + 1];
            uint32_t wa = sWa[p * 64 + lane];
            uint32_t wb = sWb[p * 64 + lane];
            acc1 += a0 * bflo(wa) + a1 * bfhi(wa);
            acc2 += a0 * bflo(wb) + a1 * bfhi(wb);
        }
        Xrow[(size_t)n * 64 + lane] = (ushort)bf16round(acc1);
        Xcol[(size_t)n * 64 + lane] = (ushort)bf16round(acc2);
        hbf[(size_t)n * 64 + lane]  = (ushort)bf16round(hn[lane]);
    }
}

// ---------------- edge kernel: row-sorted, fused row reductions ------------
__global__ __launch_bounds__(256) void edge_kernel(
    const float* __restrict__ Z,
    const uint2* __restrict__ rs_rc, const int* __restrict__ rs_pc,
    const ushort* __restrict__ Xrow, const ushort* __restrict__ Xcol,
    const float* __restrict__ We1, const float* __restrict__ We2, const float* __restrict__ be2,
    const float* __restrict__ Wc1, const float* __restrict__ bc1, const float* __restrict__ Wc2,
    ushort* __restrict__ ef_col,
    float* __restrict__ aggF, float* __restrict__ segF, int E)
{
    __shared__ ushort radT[4][16 * 32];
    __shared__ ushort h1T[4][16 * 72];
    __shared__ ushort efT[4][16 * 72];   // Xcol tile before layer2, ef after
    __shared__ ushort xrT[4][16 * 72];   // Xrow tile
    __shared__ float  cdT[4][16 * 12];   // coord_diff per edge
    __shared__ float  phiT[4][16];

    int tid   = threadIdx.x;
    int lane  = tid & 63;
    int wslot = tid >> 6;
    int l16   = lane & 15;
    int quad  = lane >> 4;

    short8 w1r[4], w2f0[4], w2f1[4], w3f0[4], w3f1[4];
    float be2v[4], bc1v[4], wc2v[4];
    #pragma unroll
    for (int nt = 0; nt < 4; nt++) {
        int n = nt * 16 + l16;
        #pragma unroll
        for (int j = 0; j < 8; j++) {
            int k = quad * 8 + j;
            w1r[nt][j]  = (k < 16) ? (short)bf16round(We1[(128 + k) * 64 + n]) : (short)0;
            w2f0[nt][j] = (short)bf16round(We2[k * 64 + n]);
            w2f1[nt][j] = (short)bf16round(We2[(32 + k) * 64 + n]);
            w3f0[nt][j] = (short)bf16round(Wc1[k * 64 + n]);
            w3f1[nt][j] = (short)bf16round(Wc1[(32 + k) * 64 + n]);
        }
        be2v[nt] = be2[n];
        bc1v[nt] = bc1[n];
        wc2v[nt] = Wc2[n];
    }

    {   // zero K=16..31 half of the radial tile once
        int e = lane >> 2, o = (lane & 3) * 4;
        *(uint2*)&radT[wslot][e * 32 + 16 + o] = make_uint2(0u, 0u);
    }

    int e_l = lane >> 2;
    int cb  = (lane & 3) * 3;

    const f32x4 z4 = {0.f, 0.f, 0.f, 0.f};
    int ntile = (E + 15) >> 4;
    for (int t = blockIdx.x * 4 + wslot; t < ntile; t += gridDim.x * 4) {
        int e0 = t * 16;
        int eidx = e0 + l16;
        int eclmp = min(eidx, E - 1);
        uint2 rcv = rs_rc[eclmp];     // coalesced 8B (sorted domain)
        int rowv = (int)rcv.x;
        int colv = (int)rcv.y;
        int pcv  = rs_pc[eclmp];

        // ---- stage Xrow/Xcol rows into LDS (uint4 loads, 8 lanes/row) ----
        {
            int off = lane & 7, es = lane >> 3;
            #pragma unroll
            for (int i = 0; i < 2; i++) {
                int e = es + i * 8;
                int nr = __shfl(rowv, e, 64);
                int nc = __shfl(colv, e, 64);
                uint4 vr = *(const uint4*)(Xrow + (size_t)nr * 64 + off * 8);
                uint4 vc = *(const uint4*)(Xcol + (size_t)nc * 64 + off * 8);
                *(uint4*)&xrT[wslot][e * 72 + off * 8] = vr;
                *(uint4*)&efT[wslot][e * 72 + off * 8] = vc;
            }
        }

        // ---- coord_diff + gram + radial (4 lanes per edge) ----
        int rZ = __shfl(rowv, e_l, 64);
        int cZ = __shfl(colv, e_l, 64);
        const float* Zr = Z + (size_t)rZ * 12 + cb;
        const float* Zc = Z + (size_t)cZ * 12 + cb;
        float cd0 = Zr[0] - Zc[0];
        float cd1 = Zr[1] - Zc[1];
        float cd2 = Zr[2] - Zc[2];
        cdT[wslot][e_l * 12 + cb + 0] = cd0;
        cdT[wslot][e_l * 12 + cb + 1] = cd1;
        cdT[wslot][e_l * 12 + cb + 2] = cd2;

        int gbase = lane & ~3;
        float g0, g1, g2, g3;
        {
            float a0 = __shfl(cd0, gbase + 0, 64), b0 = __shfl(cd1, gbase + 0, 64), c0 = __shfl(cd2, gbase + 0, 64);
            float a1 = __shfl(cd0, gbase + 1, 64), b1 = __shfl(cd1, gbase + 1, 64), c1 = __shfl(cd2, gbase + 1, 64);
            float a2 = __shfl(cd0, gbase + 2, 64), b2 = __shfl(cd1, gbase + 2, 64), c2 = __shfl(cd2, gbase + 2, 64);
            float a3 = __shfl(cd0, gbase + 3, 64), b3 = __shfl(cd1, gbase + 3, 64), c3 = __shfl(cd2, gbase + 3, 64);
            g0 = cd0 * a0 + cd1 * b0 + cd2 * c0;
            g1 = cd0 * a1 + cd1 * b1 + cd2 * c1;
            g2 = cd0 * a2 + cd1 * b2 + cd2 * c2;
            g3 = cd0 * a3 + cd1 * b3 + cd2 * c3;
        }
        float s = g0 * g0 + g1 * g1 + g2 * g2 + g3 * g3;
        s += __shfl_xor(s, 1, 64);
        s += __shfl_xor(s, 2, 64);
        float inv = 1.f / fmaxf(sqrtf(s), 1e-12f);

        __builtin_amdgcn_wave_barrier();
        uint2 rp;
        rp.x = packbf(g0 * inv, g1 * inv);
        rp.y = packbf(g2 * inv, g3 * inv);
        *(uint2*)&radT[wslot][e_l * 32 + (lane & 3) * 4] = rp;
        __builtin_amdgcn_wave_barrier();

        // ---- layer 1: radial @ We1[128:144] ----
        short8 aR = *(const short8*)&radT[wslot][l16 * 32 + quad * 8];
        f32x4 c1t[4];
        #pragma unroll
        for (int nt = 0; nt < 4; nt++)
            c1t[nt] = __builtin_amdgcn_mfma_f32_16x16x32_bf16(aR, w1r[nt], z4, 0, 0, 0);

        // ---- + Xrow + Xcol (from LDS), relu, write h1 tile ----
        __builtin_amdgcn_wave_barrier();
        #pragma unroll
        for (int nt = 0; nt < 4; nt++) {
            int n = nt * 16 + l16;
            #pragma unroll
            for (int reg = 0; reg < 4; reg++) {
                int eL = quad * 4 + reg;
                float hv = c1t[nt][reg]
                         + bfu(xrT[wslot][eL * 72 + n])
                         + bfu(efT[wslot][eL * 72 + n]);
                hv = fmaxf(hv, 0.f);
                h1T[wslot][eL * 72 + n] = (ushort)bf16round(hv);
            }
        }
        __builtin_amdgcn_wave_barrier();

        // ---- layer 2: h1 @ We2 + be2, relu -> edge_feat (overwrites efT) ----
        short8 a20 = *(const short8*)&h1T[wslot][l16 * 72 + quad * 8];
        short8 a21 = *(const short8*)&h1T[wslot][l16 * 72 + 32 + quad * 8];
        f32x4 c2t[4];
        #pragma unroll
        for (int nt = 0; nt < 4; nt++) {
            f32x4 a = __builtin_amdgcn_mfma_f32_16x16x32_bf16(a20, w2f0[nt], z4, 0, 0, 0);
            c2t[nt]  = __builtin_amdgcn_mfma_f32_16x16x32_bf16(a21, w2f1[nt], a, 0, 0, 0);
        }

        __builtin_amdgcn_wave_barrier();
        #pragma unroll
        for (int nt = 0; nt < 4; nt++) {
            int n = nt * 16 + l16;
            #pragma unroll
            for (int reg = 0; reg < 4; reg++) {
                float ef = fmaxf(c2t[nt][reg] + be2v[nt], 0.f);
                efT[wslot][(quad * 4 + reg) * 72 + n] = (ushort)bf16round(ef);
            }
        }
        __builtin_amdgcn_wave_barrier();

        // ---- ef_col: scatter full rows to col-sorted slots ----
        {
            int off = lane & 7, es = lane >> 3;
            #pragma unroll
            for (int i = 0; i < 2; i++) {
                int e = es + i * 8;
                int pc = __shfl(pcv, e, 64);
                if (e0 + e < E)
                    *(uint4*)(ef_col + (size_t)pc * 64 + off * 8) =
                        *(const uint4*)&efT[wslot][e * 72 + off * 8];
            }
        }

        // ---- layer 3: edge_feat @ Wc1 + bc1, relu, @ Wc2 -> phi ----
        short8 a30 = *(const short8*)&efT[wslot][l16 * 72 + quad * 8];
        short8 a31 = *(const short8*)&efT[wslot][l16 * 72 + 32 + quad * 8];
        float ps[4] = {0.f, 0.f, 0.f, 0.f};
        #pragma unroll
        for (int nt = 0; nt < 4; nt++) {
            f32x4 a = __builtin_amdgcn_mfma_f32_16x16x32_bf16(a30, w3f0[nt], z4, 0, 0, 0);
            f32x4 c = __builtin_amdgcn_mfma_f32_16x16x32_bf16(a31, w3f1[nt], a, 0, 0, 0);
            #pragma unroll
            for (int reg = 0; reg < 4; reg++)
                ps[reg] += fmaxf(c[reg] + bc1v[nt], 0.f) * wc2v[nt];
        }
        #pragma unroll
        for (int reg = 0; reg < 4; reg++) {
            ps[reg] += __shfl_xor(ps[reg], 1, 64);
            ps[reg] += __shfl_xor(ps[reg], 2, 64);
            ps[reg] += __shfl_xor(ps[reg], 4, 64);
            ps[reg] += __shfl_xor(ps[reg], 8, 64);
        }
        __builtin_amdgcn_wave_barrier();
        if (l16 == 0) {
            f32x4 pv = {ps[0], ps[1], ps[2], ps[3]};
            *(f32x4*)&phiT[wslot][quad * 4] = pv;
        }
        __builtin_amdgcn_wave_barrier();

        // ---- in-tile segmented reduction over row runs ----
        {
            int curnode = __shfl(rowv, 0, 64);
            int a = 0;
            float accA = 0.f, accS = 0.f;
            #pragma unroll
            for (int e = 0; e < 16; e++) {
                bool valid = (e0 + e) < E;
                float v = valid ? bfu(efT[wslot][e * 72 + lane]) : 0.f;
                float sv = 0.f;
                if (lane < 12 && valid)
                    sv = phiT[wslot][e] * cdT[wslot][e * 12 + lane];
                accA += v;
                accS += sv;
                int nxt = (e < 15) ? __shfl(rowv, e + 1, 64) : -1;
                if (nxt != curnode) {
                    if (a > 0 && e < 15) {          // whole segment inside tile
                        aggF[(size_t)curnode * 64 + lane] = accA;
                        if (lane < 12) segF[(size_t)curnode * 12 + lane] = accS;
                    } else if ((e0 + a) < E) {      // boundary run -> atomic
                        unsafeAtomicAdd(&aggF[(size_t)curnode * 64 + lane], accA);
                        if (lane < 12) unsafeAtomicAdd(&segF[(size_t)curnode * 12 + lane], accS);
                    }
                    curnode = nxt;
                    a = e + 1;
                    accA = 0.f;
                    accS = 0.f;
                }
            }
        }
        __builtin_amdgcn_wave_barrier();
    }
}

// ---------------- reduce kernel: streaming "others" only (unroll x4) -------
__global__ __launch_bounds__(256) void reduce_kernel(
    const int* __restrict__ colptr, const ushort* __restrict__ ef_col,
    ushort* __restrict__ othersB, int N)
{
    int tid = threadIdx.x;
    int lane = tid & 63, wslot = tid >> 6;
    int wv = blockIdx.x * 4 + wslot, nw = gridDim.x * 4;

    for (int n0 = wv; n0 < N; n0 += nw) {
        int n = __builtin_amdgcn_readfirstlane(n0);
        int cs = colptr[n], ceN = colptr[n + 1];
        float inv_col = 1.f / (float)max(ceN - cs, 1);

        float othv = 0.f;
        int p = cs;
        for (; p + 3 < ceN; p += 4) {
            float a = bfu(ef_col[(size_t)p * 64 + lane]);
            float b = bfu(ef_col[(size_t)(p + 1) * 64 + lane]);
            float c = bfu(ef_col[(size_t)(p + 2) * 64 + lane]);
            float d = bfu(ef_col[(size_t)(p + 3) * 64 + lane]);
            othv += (a + b) + (c + d);
        }
        for (; p < ceN; p++) othv += bfu(ef_col[(size_t)p * 64 + lane]);
        othv *= inv_col;

        othersB[(size_t)n * 64 + lane] = (ushort)bf16round(othv);
    }
}

// ---------------- mlp kernel: 16 nodes per wave, MFMA ----------------------
__global__ __launch_bounds__(256) void mlp_kernel(
    const float* __restrict__ h, const float* __restrict__ Z,
    const ushort* __restrict__ hbf,
    const float* __restrict__ aggF, const ushort* __restrict__ othersB,
    const float* __restrict__ segF, const int* __restrict__ rowptr,
    const float* __restrict__ Wn1, const float* __restrict__ bn1,
    const float* __restrict__ Wn2, const float* __restrict__ bn2,
    const float* __restrict__ Wv1, const float* __restrict__ bv1,
    const float* __restrict__ Wv2, const float* __restrict__ bv2,
    float* __restrict__ out, int N)
{
    __shared__ ushort aT[4][16 * 200];
    __shared__ ushort h1T[4][16 * 72];
    __shared__ float  scT[4][16];
    __shared__ float  irT[4][16];

    int tid   = threadIdx.x;
    int lane  = tid & 63;
    int wslot = tid >> 6;
    int l16   = lane & 15;
    int quad  = lane >> 4;

    short8 wn1f[6][4], wn2f[2][4], wv1f[2][4];
    float bn1v[4], bn2v[4], bv1v[4], wv2v[4];
    #pragma unroll
    for (int nt = 0; nt < 4; nt++) {
        int n = nt * 16 + l16;
        #pragma unroll
        for (int kc = 0; kc < 6; kc++)
            #pragma unroll
            for (int j = 0; j < 8; j++)
                wn1f[kc][nt][j] = (short)bf16round(Wn1[(kc * 32 + quad * 8 + j) * 64 + n]);
        #pragma unroll
        for (int kc = 0; kc < 2; kc++)
            #pragma unroll
            for (int j = 0; j < 8; j++) {
                wn2f[kc][nt][j] = (short)bf16round(Wn2[(kc * 32 + quad * 8 + j) * 64 + n]);
                wv1f[kc][nt][j] = (short)bf16round(Wv1[(kc * 32 + quad * 8 + j) * 64 + n]);
            }
        bn1v[nt] = bn1[n];
        bn2v[nt] = bn2[n];
        bv1v[nt] = bv1[n];
        wv2v[nt] = Wv2[n];
    }
    float bv2s = bv2[0];

    const f32x4 z4 = {0.f, 0.f, 0.f, 0.f};
    size_t OZ = (size_t)N * 64, OX = (size_t)N * 76, OV = (size_t)N * 79;
    int ntile = (N + 15) >> 4;
    for (int t = blockIdx.x * 4 + wslot; t < ntile; t += gridDim.x * 4) {
        int n0 = t * 16;

        // inv_row per node
        if (lane < 16) {
            int node = min(n0 + lane, N - 1);
            irT[wslot][lane] = 1.f / (float)max(rowptr[node + 1] - rowptr[node], 1);
        }

        // ---- stage A tile: [others | h | agg(fp32->bf16)] ----
        {
            #pragma unroll
            for (int i = 0; i < 2; i++) {
                int c = i * 64 + lane;
                int r = c >> 3, off = c & 7;
                int nn = min(n0 + r, N - 1);
                uint4 vo = *(const uint4*)(othersB + (size_t)nn * 64 + off * 8);
                uint4 vh = *(const uint4*)(hbf     + (size_t)nn * 64 + off * 8);
                float4 f0 = *(const float4*)(aggF + (size_t)nn * 64 + off * 8);
                float4 f1 = *(const float4*)(aggF + (size_t)nn * 64 + off * 8 + 4);
                uint4 va = make_uint4(packbf(f0.x, f0.y), packbf(f0.z, f0.w),
                                      packbf(f1.x, f1.y), packbf(f1.z, f1.w));
                *(uint4*)&aT[wslot][r * 200 +       off * 8] = vo;
                *(uint4*)&aT[wslot][r * 200 +  64 + off * 8] = vh;
                *(uint4*)&aT[wslot][r * 200 + 128 + off * 8] = va;
            }
        }
        __builtin_amdgcn_wave_barrier();

        // ---- Z_new = Z + segF/cnt (12 comps per node) ----
        #pragma unroll
        for (int i = 0; i < 4; i++) {
            int nd = i * 4 + (lane >> 4);
            int comp = lane & 15;
            int node = n0 + nd;
            if (comp < 12 && node < N) {
                float f = segF[(size_t)node * 12 + comp] * irT[wslot][nd];
                out[OZ + (size_t)node * 12 + comp] = Z[(size_t)node * 12 + comp] + f;
            }
        }

        // ---- layer 1: A @ Wn1 + bn1, relu ----
        f32x4 c1t[4];
        short8 af[6];
        #pragma unroll
        for (int kc = 0; kc < 6; kc++)
            af[kc] = *(const short8*)&aT[wslot][l16 * 200 + kc * 32 + quad * 8];
        #pragma unroll
        for (int nt = 0; nt < 4; nt++) {
            f32x4 c = z4;
            #pragma unroll
            for (int kc = 0; kc < 6; kc++)
                c = __builtin_amdgcn_mfma_f32_16x16x32_bf16(af[kc], wn1f[kc][nt], c, 0, 0, 0);
            c1t[nt] = c;
        }
        __builtin_amdgcn_wave_barrier();
        #pragma unroll
        for (int nt = 0; nt < 4; nt++) {
            int n = nt * 16 + l16;
            #pragma unroll
            for (int reg = 0; reg < 4; reg++) {
                float hv = fmaxf(c1t[nt][reg] + bn1v[nt], 0.f);
                h1T[wslot][(quad * 4 + reg) * 72 + n] = (ushort)bf16round(hv);
            }
        }
        __builtin_amdgcn_wave_barrier();

        // ---- layer 2: h1 @ Wn2 + bn2; h_new = h + . ----
        short8 a20 = *(const short8*)&h1T[wslot][l16 * 72 + quad * 8];
        short8 a21 = *(const short8*)&h1T[wslot][l16 * 72 + 32 + quad * 8];
        f32x4 hnewT[4];
        #pragma unroll
        for (int nt = 0; nt < 4; nt++) {
            f32x4 a = __builtin_amdgcn_mfma_f32_16x16x32_bf16(a20, wn2f[0][nt], z4, 0, 0, 0);
            f32x4 c = __builtin_amdgcn_mfma_f32_16x16x32_bf16(a21, wn2f[1][nt], a, 0, 0, 0);
            int n = nt * 16 + l16;
            #pragma unroll
            for (int reg = 0; reg < 4; reg++) {
                int node = n0 + quad * 4 + reg;
                int nc = min(node, N - 1);
                float hnew = h[(size_t)nc * 64 + n] + c[reg] + bn2v[nt];
                hnewT[nt][reg] = hnew;
                if (node < N) out[(size_t)node * 64 + n] = hnew;
            }
        }

        // ---- vel mlp ----
        __builtin_amdgcn_wave_barrier();
        #pragma unroll
        for (int nt = 0; nt < 4; nt++) {
            int n = nt * 16 + l16;
            #pragma unroll
            for (int reg = 0; reg < 4; reg++)
                h1T[wslot][(quad * 4 + reg) * 72 + n] = (ushort)bf16round(hnewT[nt][reg]);
        }
        __builtin_amdgcn_wave_barrier();
        short8 a30 = *(const short8*)&h1T[wslot][l16 * 72 + quad * 8];
        short8 a31 = *(const short8*)&h1T[wslot][l16 * 72 + 32 + quad * 8];
        float ps[4] = {0.f, 0.f, 0.f, 0.f};
        #pragma unroll
        for (int nt = 0; nt < 4; nt++) {
            f32x4 a = __builtin_amdgcn_mfma_f32_16x16x32_bf16(a30, wv1f[0][nt], z4, 0, 0, 0);
            f32x4 c = __builtin_amdgcn_mfma_f32_16x16x32_bf16(a31, wv1f[1][nt], a, 0, 0, 0);
            #pragma unroll
            for (int reg = 0; reg < 4; reg++)
                ps[reg] += fmaxf(c[reg] + bv1v[nt], 0.f) * wv2v[nt];
        }
        #pragma unroll
        for (int reg = 0; reg < 4; reg++) {
            ps[reg] += __shfl_xor(ps[reg], 1, 64);
            ps[reg] += __shfl_xor(ps[reg], 2, 64);
            ps[reg] += __shfl_xor(ps[reg], 4, 64);
            ps[reg] += __shfl_xor(ps[reg], 8, 64);
        }
        __builtin_amdgcn_wave_barrier();
        if (l16 == 0) {
            f32x4 pv = {ps[0] + bv2s, ps[1] + bv2s, ps[2] + bv2s, ps[3] + bv2s};
            *(f32x4*)&scT[wslot][quad * 4] = pv;
        }
        __builtin_amdgcn_wave_barrier();

        // ---- x_new / v_new ----
        if (lane < 48) {
            int nd = lane / 3, comp = lane - nd * 3;
            int node = n0 + nd;
            if (node < N) {
                float scale = scT[wslot][nd];
                float f = segF[(size_t)node * 12 + comp] * irT[wslot][nd];
                float v = scale * Z[(size_t)node * 12 + 3 + comp] + f;
                float x = Z[(size_t)node * 12 + comp] + v;
                out[OX + (size_t)node * 3 + comp] = x;
                out[OV + (size_t)node * 3 + comp] = v;
            }
        }
        __builtin_amdgcn_wave_barrier();
    }
}

extern "C" void kernel_launch(void* const* d_in, const int* in_sizes, int n_in,
                              void* d_out, int out_size, void* d_ws, size_t ws_size,
                              hipStream_t stream) {
    const float* h   = (const float*)d_in[0];
    const float* Z   = (const float*)d_in[1];
    const int*   row = (const int*)d_in[2];
    const int*   col = (const int*)d_in[3];
    const float* We1 = (const float*)d_in[4];
    const float* be1 = (const float*)d_in[5];
    const float* We2 = (const float*)d_in[6];
    const float* be2 = (const float*)d_in[7];
    const float* Wn1 = (const float*)d_in[8];
    const float* bn1 = (const float*)d_in[9];
    const float* Wn2 = (const float*)d_in[10];
    const float* bn2 = (const float*)d_in[11];
    const float* Wc1 = (const float*)d_in[12];
    const float* bc1 = (const float*)d_in[13];
    const float* Wc2 = (const float*)d_in[14];
    const float* Wv1 = (const float*)d_in[15];
    const float* bv1 = (const float*)d_in[16];
    const float* Wv2 = (const float*)d_in[17];
    const float* bv2 = (const float*)d_in[18];

    int N = in_sizes[0] / 64;
    int E = in_sizes[2];
    int nblk = (N + 1023) / 1024;

    // workspace layout; zeroed region first (cnt + fp32 accumulators)
    char* ws = (char*)d_ws;
    size_t o = 0;
    int* cntR    = (int*)(ws + o); o += (size_t)N * 4;
    int* cntC    = (int*)(ws + o); o += (size_t)N * 4;
    float* aggF  = (float*)(ws + o); o += (size_t)N * 64 * 4;   // 12.8 MB
    float* segF  = (float*)(ws + o); o += (size_t)N * 12 * 4;   //  2.4 MB
    size_t zero_bytes = o;
    int* rowptr  = (int*)(ws + o); o += (size_t)(N + 1) * 4;
    int* colptr  = (int*)(ws + o); o += (size_t)(N + 1) * 4;
    int* bsumR   = (int*)(ws + o); o += (size_t)nblk * 4;
    int* bsumC   = (int*)(ws + o); o += (size_t)nblk * 4;
    int* rank_r  = (int*)(ws + o); o += (size_t)E * 4;
    int* rank_c  = (int*)(ws + o); o += (size_t)E * 4;
    o = (o + 15) & ~(size_t)15;
    uint2* rs_rc = (uint2*)(ws + o); o += (size_t)E * 8;        // 6.4 MB
    int* rs_pc   = (int*)(ws + o); o += (size_t)E * 4;          // 3.2 MB
    ushort* Xrow = (ushort*)(ws + o); o += (size_t)N * 64 * 2;
    ushort* Xcol = (ushort*)(ws + o); o += (size_t)N * 64 * 2;
    ushort* hbf  = (ushort*)(ws + o); o += (size_t)N * 64 * 2;
    ushort* othersB = (ushort*)(ws + o); o += (size_t)N * 64 * 2;
    ushort* ef_col = (ushort*)(ws + o); o += (size_t)E * 64 * 2;  // 102.4 MB
    float* out = (float*)d_out;

    hipMemsetAsync(d_ws, 0, zero_bytes, stream);
    hist_rank<<<1024, 256, 0, stream>>>(row, col, cntR, cntC, rank_r, rank_c, E);
    scan_block<<<dim3(nblk, 2), 1024, 0, stream>>>(cntR, cntC, rowptr, colptr,
                                                   bsumR, bsumC, N);
    scan_totals<<<1, 64, 0, stream>>>(bsumR, bsumC, rowptr, colptr, nblk, N);
    scan_add<<<dim3(nblk, 2), 1024, 0, stream>>>(rowptr, colptr, bsumR, bsumC, N);
    perm_build<<<1024, 256, 0, stream>>>(row, col, rowptr, colptr,
                                         rank_r, rank_c, rs_rc, rs_pc, E);
    precompute_xrowcol<<<512, 256, 0, stream>>>(h, We1, be1, Xrow, Xcol, hbf, N);
    edge_kernel<<<1024, 256, 0, stream>>>(Z, rs_rc, rs_pc, Xrow, Xcol,
                                          We1, We2, be2, Wc1, bc1, Wc2,
                                          ef_col, aggF, segF, E);
    reduce_kernel<<<2048, 256, 0, stream>>>(colptr, ef_col, othersB, N);
    mlp_kernel<<<800, 256, 0, stream>>>(h, Z, hbf, aggF, othersB, segF, rowptr,
                                        Wn1, bn1, Wn2, bn2, Wv1, bv1, Wv2, bv2,
                                        out, N);
}

// Round 12
// 455.102 us; speedup vs baseline: 1.1958x; 1.0224x over previous
//
#include <hip/hip_runtime.h>
#include <stdint.h>

// GMN/EGNN layer: N=50000, E=800000, F_IN=HID=64, RADIAL=16.
// R12 = R11 (465us) with two amortization fixes to sub-top kernels:
//  - mlp grid 800->200: the ~1300-instr weight-preload prologue was amortized
//    over ONE 16-node tile per wave; now 4 tiles/wave.
//  - reduce: two-row uint2 loads (lanes 0-31 row p, 32-63 row p+1, shfl merge),
//    unroll 4 -> 2x bytes/instr in a latency-bound stream.
// Edge kernel frozen (155us across 3 builds; R10 taught occupancy-critical).

__device__ __forceinline__ uint32_t bf16round(float x) {
    uint32_t u = __float_as_uint(x);
    return (u + 0x7fffu + ((u >> 16) & 1u)) >> 16;
}
__device__ __forceinline__ uint32_t packbf(float a, float b) {
    return bf16round(a) | (bf16round(b) << 16);
}
__device__ __forceinline__ float bflo(uint32_t u) { return __uint_as_float(u << 16); }
__device__ __forceinline__ float bfhi(uint32_t u) { return __uint_as_float(u & 0xffff0000u); }
__device__ __forceinline__ float bfu(ushort u) { return __uint_as_float(((uint32_t)u) << 16); }

typedef __attribute__((ext_vector_type(8))) short short8;
typedef __attribute__((ext_vector_type(4))) float f32x4;

__device__ __forceinline__ int wave_incl_scan(int x) {
    int lane = threadIdx.x & 63;
    #pragma unroll
    for (int off = 1; off < 64; off <<= 1) {
        int y = __shfl_up(x, off, 64);
        if (lane >= off) x += y;
    }
    return x;
}

// ---------------- hist + rank ----------------------------------------------
__global__ __launch_bounds__(256) void hist_rank(
    const int* __restrict__ row, const int* __restrict__ col,
    int* __restrict__ cntR, int* __restrict__ cntC,
    int* __restrict__ rank_r, int* __restrict__ rank_c, int E)
{
    int i = blockIdx.x * blockDim.x + threadIdx.x;
    int stride = gridDim.x * blockDim.x;
    for (; i < E; i += stride) {
        rank_r[i] = atomicAdd(&cntR[row[i]], 1);
        rank_c[i] = atomicAdd(&cntC[col[i]], 1);
    }
}

// ---------------- hierarchical exclusive scan ------------------------------
__global__ __launch_bounds__(1024) void scan_block(
    const int* __restrict__ srcR, const int* __restrict__ srcC,
    int* __restrict__ dstR, int* __restrict__ dstC,
    int* __restrict__ bsumR, int* __restrict__ bsumC, int N)
{
    const int* src = blockIdx.y ? srcC : srcR;
    int* dst  = blockIdx.y ? dstC : dstR;
    int* bsum = blockIdx.y ? bsumC : bsumR;
    __shared__ int s[17];
    int tid = threadIdx.x, lane = tid & 63, wid = tid >> 6;
    int i = blockIdx.x * 1024 + tid;
    int x = (i < N) ? src[i] : 0;
    int incl = wave_incl_scan(x);
    if (lane == 63) s[wid] = incl;
    __syncthreads();
    if (wid == 0) {
        int t = (lane < 16) ? s[lane] : 0;
        int sc = t;
        #pragma unroll
        for (int off = 1; off < 16; off <<= 1) {
            int y = __shfl_up(sc, off, 64);
            if (lane >= off) sc += y;
        }
        if (lane < 16) s[lane] = sc - t;
        if (lane == 15) s[16] = sc;
    }
    __syncthreads();
    if (i < N) dst[i] = s[wid] + incl - x;
    if (tid == 0) bsum[blockIdx.x] = s[16];
}

__global__ __launch_bounds__(64) void scan_totals(
    int* __restrict__ bsumR, int* __restrict__ bsumC,
    int* __restrict__ dstR, int* __restrict__ dstC, int nblk, int N)
{
    int lane = threadIdx.x;
    for (int which = 0; which < 2; which++) {
        int* bs = which ? bsumC : bsumR;
        int* dst = which ? dstC : dstR;
        int running = 0;
        for (int base = 0; base < nblk; base += 64) {
            int idx = base + lane;
            int x = (idx < nblk) ? bs[idx] : 0;
            int incl = wave_incl_scan(x);
            if (idx < nblk) bs[idx] = running + incl - x;   // exclusive offsets
            running += __shfl(incl, 63, 64);
        }
        if (lane == 0) dst[N] = running;                     // grand total
    }
}

__global__ __launch_bounds__(1024) void scan_add(
    int* __restrict__ dstR, int* __restrict__ dstC,
    const int* __restrict__ bsumR, const int* __restrict__ bsumC, int N)
{
    int* dst = blockIdx.y ? dstC : dstR;
    const int* bsum = blockIdx.y ? bsumC : bsumR;
    int i = blockIdx.x * 1024 + threadIdx.x;
    if (i < N) dst[i] += bsum[blockIdx.x];
}

// ---------------- perm build: uint2(row,col) + dword(pc) scatter -----------
__global__ __launch_bounds__(256) void perm_build(
    const int* __restrict__ row, const int* __restrict__ col,
    const int* __restrict__ rowptr, const int* __restrict__ colptr,
    const int* __restrict__ rank_r, const int* __restrict__ rank_c,
    uint2* __restrict__ rs_rc, int* __restrict__ rs_pc, int E)
{
    int i = blockIdx.x * blockDim.x + threadIdx.x;
    int stride = gridDim.x * blockDim.x;
    for (; i < E; i += stride) {
        int r = row[i], c = col[i];
        int pr = rowptr[r] + rank_r[i];
        int pc = colptr[c] + rank_c[i];
        rs_rc[pr] = make_uint2((uint32_t)r, (uint32_t)c);
        rs_pc[pr] = pc;
    }
}

// ---------------- precompute: Xrow/Xcol + hbf ------------------------------
__global__ __launch_bounds__(256) void precompute_xrowcol(
    const float* __restrict__ h, const float* __restrict__ We1,
    const float* __restrict__ be1,
    ushort* __restrict__ Xrow, ushort* __restrict__ Xcol,
    ushort* __restrict__ hbf, int N)
{
    __shared__ uint32_t sWa[32 * 64];
    __shared__ uint32_t sWb[32 * 64];
    __shared__ float sbe1[64];
    int tid = threadIdx.x;
    for (int idx = tid; idx < 32 * 64; idx += 256) {
        int p = idx >> 6, o = idx & 63;
        sWa[idx] = packbf(We1[(2 * p) * 64 + o],      We1[(2 * p + 1) * 64 + o]);
        sWb[idx] = packbf(We1[(64 + 2 * p) * 64 + o], We1[(64 + 2 * p + 1) * 64 + o]);
    }
    if (tid < 64) sbe1[tid] = be1[tid];
    __syncthreads();

    int lane = tid & 63;
    int wv = blockIdx.x * 4 + (tid >> 6);
    int nw = gridDim.x * 4;
    for (int n0 = wv; n0 < N; n0 += nw) {
        int n = __builtin_amdgcn_readfirstlane(n0);
        const float* hn = h + (size_t)n * 64;
        float acc1 = sbe1[lane], acc2 = 0.f;
        #pragma unroll 8
        for (int p = 0; p < 32; p++) {
            float a0 = hn[2 * p], a1 = hn[2 * p + 1];
            uint32_t wa = sWa[p * 64 + lane];
            uint32_t wb = sWb[p * 64 + lane];
            acc1 += a0 * bflo(wa) + a1 * bfhi(wa);
            acc2 += a0 * bflo(wb) + a1 * bfhi(wb);
        }
        Xrow[(size_t)n * 64 + lane] = (ushort)bf16round(acc1);
        Xcol[(size_t)n * 64 + lane] = (ushort)bf16round(acc2);
        hbf[(size_t)n * 64 + lane]  = (ushort)bf16round(hn[lane]);
    }
}

// ---------------- edge kernel: row-sorted, fused row reductions ------------
__global__ __launch_bounds__(256) void edge_kernel(
    const float* __restrict__ Z,
    const uint2* __restrict__ rs_rc, const int* __restrict__ rs_pc,
    const ushort* __restrict__ Xrow, const ushort* __restrict__ Xcol,
    const float* __restrict__ We1, const float* __restrict__ We2, const float* __restrict__ be2,
    const float* __restrict__ Wc1, const float* __restrict__ bc1, const float* __restrict__ Wc2,
    ushort* __restrict__ ef_col,
    float* __restrict__ aggF, float* __restrict__ segF, int E)
{
    __shared__ ushort radT[4][16 * 32];
    __shared__ ushort h1T[4][16 * 72];
    __shared__ ushort efT[4][16 * 72];   // Xcol tile before layer2, ef after
    __shared__ ushort xrT[4][16 * 72];   // Xrow tile
    __shared__ float  cdT[4][16 * 12];   // coord_diff per edge
    __shared__ float  phiT[4][16];

    int tid   = threadIdx.x;
    int lane  = tid & 63;
    int wslot = tid >> 6;
    int l16   = lane & 15;
    int quad  = lane >> 4;

    short8 w1r[4], w2f0[4], w2f1[4], w3f0[4], w3f1[4];
    float be2v[4], bc1v[4], wc2v[4];
    #pragma unroll
    for (int nt = 0; nt < 4; nt++) {
        int n = nt * 16 + l16;
        #pragma unroll
        for (int j = 0; j < 8; j++) {
            int k = quad * 8 + j;
            w1r[nt][j]  = (k < 16) ? (short)bf16round(We1[(128 + k) * 64 + n]) : (short)0;
            w2f0[nt][j] = (short)bf16round(We2[k * 64 + n]);
            w2f1[nt][j] = (short)bf16round(We2[(32 + k) * 64 + n]);
            w3f0[nt][j] = (short)bf16round(Wc1[k * 64 + n]);
            w3f1[nt][j] = (short)bf16round(Wc1[(32 + k) * 64 + n]);
        }
        be2v[nt] = be2[n];
        bc1v[nt] = bc1[n];
        wc2v[nt] = Wc2[n];
    }

    {   // zero K=16..31 half of the radial tile once
        int e = lane >> 2, o = (lane & 3) * 4;
        *(uint2*)&radT[wslot][e * 32 + 16 + o] = make_uint2(0u, 0u);
    }

    int e_l = lane >> 2;
    int cb  = (lane & 3) * 3;

    const f32x4 z4 = {0.f, 0.f, 0.f, 0.f};
    int ntile = (E + 15) >> 4;
    for (int t = blockIdx.x * 4 + wslot; t < ntile; t += gridDim.x * 4) {
        int e0 = t * 16;
        int eidx = e0 + l16;
        int eclmp = min(eidx, E - 1);
        uint2 rcv = rs_rc[eclmp];     // coalesced 8B (sorted domain)
        int rowv = (int)rcv.x;
        int colv = (int)rcv.y;
        int pcv  = rs_pc[eclmp];

        // ---- stage Xrow/Xcol rows into LDS (uint4 loads, 8 lanes/row) ----
        {
            int off = lane & 7, es = lane >> 3;
            #pragma unroll
            for (int i = 0; i < 2; i++) {
                int e = es + i * 8;
                int nr = __shfl(rowv, e, 64);
                int nc = __shfl(colv, e, 64);
                uint4 vr = *(const uint4*)(Xrow + (size_t)nr * 64 + off * 8);
                uint4 vc = *(const uint4*)(Xcol + (size_t)nc * 64 + off * 8);
                *(uint4*)&xrT[wslot][e * 72 + off * 8] = vr;
                *(uint4*)&efT[wslot][e * 72 + off * 8] = vc;
            }
        }

        // ---- coord_diff + gram + radial (4 lanes per edge) ----
        int rZ = __shfl(rowv, e_l, 64);
        int cZ = __shfl(colv, e_l, 64);
        const float* Zr = Z + (size_t)rZ * 12 + cb;
        const float* Zc = Z + (size_t)cZ * 12 + cb;
        float cd0 = Zr[0] - Zc[0];
        float cd1 = Zr[1] - Zc[1];
        float cd2 = Zr[2] - Zc[2];
        cdT[wslot][e_l * 12 + cb + 0] = cd0;
        cdT[wslot][e_l * 12 + cb + 1] = cd1;
        cdT[wslot][e_l * 12 + cb + 2] = cd2;

        int gbase = lane & ~3;
        float g0, g1, g2, g3;
        {
            float a0 = __shfl(cd0, gbase + 0, 64), b0 = __shfl(cd1, gbase + 0, 64), c0 = __shfl(cd2, gbase + 0, 64);
            float a1 = __shfl(cd0, gbase + 1, 64), b1 = __shfl(cd1, gbase + 1, 64), c1 = __shfl(cd2, gbase + 1, 64);
            float a2 = __shfl(cd0, gbase + 2, 64), b2 = __shfl(cd1, gbase + 2, 64), c2 = __shfl(cd2, gbase + 2, 64);
            float a3 = __shfl(cd0, gbase + 3, 64), b3 = __shfl(cd1, gbase + 3, 64), c3 = __shfl(cd2, gbase + 3, 64);
            g0 = cd0 * a0 + cd1 * b0 + cd2 * c0;
            g1 = cd0 * a1 + cd1 * b1 + cd2 * c1;
            g2 = cd0 * a2 + cd1 * b2 + cd2 * c2;
            g3 = cd0 * a3 + cd1 * b3 + cd2 * c3;
        }
        float s = g0 * g0 + g1 * g1 + g2 * g2 + g3 * g3;
        s += __shfl_xor(s, 1, 64);
        s += __shfl_xor(s, 2, 64);
        float inv = 1.f / fmaxf(sqrtf(s), 1e-12f);

        __builtin_amdgcn_wave_barrier();
        uint2 rp;
        rp.x = packbf(g0 * inv, g1 * inv);
        rp.y = packbf(g2 * inv, g3 * inv);
        *(uint2*)&radT[wslot][e_l * 32 + (lane & 3) * 4] = rp;
        __builtin_amdgcn_wave_barrier();

        // ---- layer 1: radial @ We1[128:144] ----
        short8 aR = *(const short8*)&radT[wslot][l16 * 32 + quad * 8];
        f32x4 c1t[4];
        #pragma unroll
        for (int nt = 0; nt < 4; nt++)
            c1t[nt] = __builtin_amdgcn_mfma_f32_16x16x32_bf16(aR, w1r[nt], z4, 0, 0, 0);

        // ---- + Xrow + Xcol (from LDS), relu, write h1 tile ----
        __builtin_amdgcn_wave_barrier();
        #pragma unroll
        for (int nt = 0; nt < 4; nt++) {
            int n = nt * 16 + l16;
            #pragma unroll
            for (int reg = 0; reg < 4; reg++) {
                int eL = quad * 4 + reg;
                float hv = c1t[nt][reg]
                         + bfu(xrT[wslot][eL * 72 + n])
                         + bfu(efT[wslot][eL * 72 + n]);
                hv = fmaxf(hv, 0.f);
                h1T[wslot][eL * 72 + n] = (ushort)bf16round(hv);
            }
        }
        __builtin_amdgcn_wave_barrier();

        // ---- layer 2: h1 @ We2 + be2, relu -> edge_feat (overwrites efT) ----
        short8 a20 = *(const short8*)&h1T[wslot][l16 * 72 + quad * 8];
        short8 a21 = *(const short8*)&h1T[wslot][l16 * 72 + 32 + quad * 8];
        f32x4 c2t[4];
        #pragma unroll
        for (int nt = 0; nt < 4; nt++) {
            f32x4 a = __builtin_amdgcn_mfma_f32_16x16x32_bf16(a20, w2f0[nt], z4, 0, 0, 0);
            c2t[nt]  = __builtin_amdgcn_mfma_f32_16x16x32_bf16(a21, w2f1[nt], a, 0, 0, 0);
        }

        __builtin_amdgcn_wave_barrier();
        #pragma unroll
        for (int nt = 0; nt < 4; nt++) {
            int n = nt * 16 + l16;
            #pragma unroll
            for (int reg = 0; reg < 4; reg++) {
                float ef = fmaxf(c2t[nt][reg] + be2v[nt], 0.f);
                efT[wslot][(quad * 4 + reg) * 72 + n] = (ushort)bf16round(ef);
            }
        }
        __builtin_amdgcn_wave_barrier();

        // ---- ef_col: scatter full rows to col-sorted slots ----
        {
            int off = lane & 7, es = lane >> 3;
            #pragma unroll
            for (int i = 0; i < 2; i++) {
                int e = es + i * 8;
                int pc = __shfl(pcv, e, 64);
                if (e0 + e < E)
                    *(uint4*)(ef_col + (size_t)pc * 64 + off * 8) =
                        *(const uint4*)&efT[wslot][e * 72 + off * 8];
            }
        }

        // ---- layer 3: edge_feat @ Wc1 + bc1, relu, @ Wc2 -> phi ----
        short8 a30 = *(const short8*)&efT[wslot][l16 * 72 + quad * 8];
        short8 a31 = *(const short8*)&efT[wslot][l16 * 72 + 32 + quad * 8];
        float ps[4] = {0.f, 0.f, 0.f, 0.f};
        #pragma unroll
        for (int nt = 0; nt < 4; nt++) {
            f32x4 a = __builtin_amdgcn_mfma_f32_16x16x32_bf16(a30, w3f0[nt], z4, 0, 0, 0);
            f32x4 c = __builtin_amdgcn_mfma_f32_16x16x32_bf16(a31, w3f1[nt], a, 0, 0, 0);
            #pragma unroll
            for (int reg = 0; reg < 4; reg++)
                ps[reg] += fmaxf(c[reg] + bc1v[nt], 0.f) * wc2v[nt];
        }
        #pragma unroll
        for (int reg = 0; reg < 4; reg++) {
            ps[reg] += __shfl_xor(ps[reg], 1, 64);
            ps[reg] += __shfl_xor(ps[reg], 2, 64);
            ps[reg] += __shfl_xor(ps[reg], 4, 64);
            ps[reg] += __shfl_xor(ps[reg], 8, 64);
        }
        __builtin_amdgcn_wave_barrier();
        if (l16 == 0) {
            f32x4 pv = {ps[0], ps[1], ps[2], ps[3]};
            *(f32x4*)&phiT[wslot][quad * 4] = pv;
        }
        __builtin_amdgcn_wave_barrier();

        // ---- in-tile segmented reduction over row runs ----
        {
            int curnode = __shfl(rowv, 0, 64);
            int a = 0;
            float accA = 0.f, accS = 0.f;
            #pragma unroll
            for (int e = 0; e < 16; e++) {
                bool valid = (e0 + e) < E;
                float v = valid ? bfu(efT[wslot][e * 72 + lane]) : 0.f;
                float sv = 0.f;
                if (lane < 12 && valid)
                    sv = phiT[wslot][e] * cdT[wslot][e * 12 + lane];
                accA += v;
                accS += sv;
                int nxt = (e < 15) ? __shfl(rowv, e + 1, 64) : -1;
                if (nxt != curnode) {
                    if (a > 0 && e < 15) {          // whole segment inside tile
                        aggF[(size_t)curnode * 64 + lane] = accA;
                        if (lane < 12) segF[(size_t)curnode * 12 + lane] = accS;
                    } else if ((e0 + a) < E) {      // boundary run -> atomic
                        unsafeAtomicAdd(&aggF[(size_t)curnode * 64 + lane], accA);
                        if (lane < 12) unsafeAtomicAdd(&segF[(size_t)curnode * 12 + lane], accS);
                    }
                    curnode = nxt;
                    a = e + 1;
                    accA = 0.f;
                    accS = 0.f;
                }
            }
        }
        __builtin_amdgcn_wave_barrier();
    }
}

// ---------------- reduce kernel: two-row uint2 streaming -------------------
__global__ __launch_bounds__(256) void reduce_kernel(
    const int* __restrict__ colptr, const ushort* __restrict__ ef_col,
    ushort* __restrict__ othersB, int N)
{
    int tid = threadIdx.x;
    int lane = tid & 63, wslot = tid >> 6;
    int half = lane >> 5;          // 0: even row, 1: odd row
    int l32  = lane & 31;          // feature pair base = 2*l32
    int wv = blockIdx.x * 4 + wslot, nw = gridDim.x * 4;

    for (int n0 = wv; n0 < N; n0 += nw) {
        int n = __builtin_amdgcn_readfirstlane(n0);
        int cs = colptr[n], ceN = colptr[n + 1];
        float inv_col = 1.f / (float)max(ceN - cs, 1);

        float f0 = 0.f, f1 = 0.f;
        int p = cs;
        for (; p + 7 < ceN; p += 8) {
            #pragma unroll
            for (int u = 0; u < 4; u++) {
                int r = p + u * 2 + half;
                uint32_t v = *(const uint32_t*)(ef_col + (size_t)r * 64 + l32 * 2);
                f0 += bflo(v);
                f1 += bfhi(v);
            }
        }
        for (; p < ceN; p += 2) {
            int r = p + half;
            if (r < ceN) {
                uint32_t v = *(const uint32_t*)(ef_col + (size_t)r * 64 + l32 * 2);
                f0 += bflo(v);
                f1 += bfhi(v);
            }
        }
        f0 += __shfl_xor(f0, 32, 64);
        f1 += __shfl_xor(f1, 32, 64);
        if (lane < 32) {
            uint32_t pk = packbf(f0 * inv_col, f1 * inv_col);
            *(uint32_t*)&othersB[(size_t)n * 64 + l32 * 2] = pk;
        }
    }
}

// ---------------- mlp kernel: 16 nodes per wave, MFMA ----------------------
__global__ __launch_bounds__(256) void mlp_kernel(
    const float* __restrict__ h, const float* __restrict__ Z,
    const ushort* __restrict__ hbf,
    const float* __restrict__ aggF, const ushort* __restrict__ othersB,
    const float* __restrict__ segF, const int* __restrict__ rowptr,
    const float* __restrict__ Wn1, const float* __restrict__ bn1,
    const float* __restrict__ Wn2, const float* __restrict__ bn2,
    const float* __restrict__ Wv1, const float* __restrict__ bv1,
    const float* __restrict__ Wv2, const float* __restrict__ bv2,
    float* __restrict__ out, int N)
{
    __shared__ ushort aT[4][16 * 200];
    __shared__ ushort h1T[4][16 * 72];
    __shared__ float  scT[4][16];
    __shared__ float  irT[4][16];

    int tid   = threadIdx.x;
    int lane  = tid & 63;
    int wslot = tid >> 6;
    int l16   = lane & 15;
    int quad  = lane >> 4;

    short8 wn1f[6][4], wn2f[2][4], wv1f[2][4];
    float bn1v[4], bn2v[4], bv1v[4], wv2v[4];
    #pragma unroll
    for (int nt = 0; nt < 4; nt++) {
        int n = nt * 16 + l16;
        #pragma unroll
        for (int kc = 0; kc < 6; kc++)
            #pragma unroll
            for (int j = 0; j < 8; j++)
                wn1f[kc][nt][j] = (short)bf16round(Wn1[(kc * 32 + quad * 8 + j) * 64 + n]);
        #pragma unroll
        for (int kc = 0; kc < 2; kc++)
            #pragma unroll
            for (int j = 0; j < 8; j++) {
                wn2f[kc][nt][j] = (short)bf16round(Wn2[(kc * 32 + quad * 8 + j) * 64 + n]);
                wv1f[kc][nt][j] = (short)bf16round(Wv1[(kc * 32 + quad * 8 + j) * 64 + n]);
            }
        bn1v[nt] = bn1[n];
        bn2v[nt] = bn2[n];
        bv1v[nt] = bv1[n];
        wv2v[nt] = Wv2[n];
    }
    float bv2s = bv2[0];

    const f32x4 z4 = {0.f, 0.f, 0.f, 0.f};
    size_t OZ = (size_t)N * 64, OX = (size_t)N * 76, OV = (size_t)N * 79;
    int ntile = (N + 15) >> 4;
    for (int t = blockIdx.x * 4 + wslot; t < ntile; t += gridDim.x * 4) {
        int n0 = t * 16;

        // inv_row per node
        if (lane < 16) {
            int node = min(n0 + lane, N - 1);
            irT[wslot][lane] = 1.f / (float)max(rowptr[node + 1] - rowptr[node], 1);
        }

        // ---- stage A tile: [others | h | agg(fp32->bf16)] ----
        {
            #pragma unroll
            for (int i = 0; i < 2; i++) {
                int c = i * 64 + lane;
                int r = c >> 3, off = c & 7;
                int nn = min(n0 + r, N - 1);
                uint4 vo = *(const uint4*)(othersB + (size_t)nn * 64 + off * 8);
                uint4 vh = *(const uint4*)(hbf     + (size_t)nn * 64 + off * 8);
                float4 f0 = *(const float4*)(aggF + (size_t)nn * 64 + off * 8);
                float4 f1 = *(const float4*)(aggF + (size_t)nn * 64 + off * 8 + 4);
                uint4 va = make_uint4(packbf(f0.x, f0.y), packbf(f0.z, f0.w),
                                      packbf(f1.x, f1.y), packbf(f1.z, f1.w));
                *(uint4*)&aT[wslot][r * 200 +       off * 8] = vo;
                *(uint4*)&aT[wslot][r * 200 +  64 + off * 8] = vh;
                *(uint4*)&aT[wslot][r * 200 + 128 + off * 8] = va;
            }
        }
        __builtin_amdgcn_wave_barrier();

        // ---- Z_new = Z + segF/cnt (12 comps per node) ----
        #pragma unroll
        for (int i = 0; i < 4; i++) {
            int nd = i * 4 + (lane >> 4);
            int comp = lane & 15;
            int node = n0 + nd;
            if (comp < 12 && node < N) {
                float f = segF[(size_t)node * 12 + comp] * irT[wslot][nd];
                out[OZ + (size_t)node * 12 + comp] = Z[(size_t)node * 12 + comp] + f;
            }
        }

        // ---- layer 1: A @ Wn1 + bn1, relu ----
        f32x4 c1t[4];
        short8 af[6];
        #pragma unroll
        for (int kc = 0; kc < 6; kc++)
            af[kc] = *(const short8*)&aT[wslot][l16 * 200 + kc * 32 + quad * 8];
        #pragma unroll
        for (int nt = 0; nt < 4; nt++) {
            f32x4 c = z4;
            #pragma unroll
            for (int kc = 0; kc < 6; kc++)
                c = __builtin_amdgcn_mfma_f32_16x16x32_bf16(af[kc], wn1f[kc][nt], c, 0, 0, 0);
            c1t[nt] = c;
        }
        __builtin_amdgcn_wave_barrier();
        #pragma unroll
        for (int nt = 0; nt < 4; nt++) {
            int n = nt * 16 + l16;
            #pragma unroll
            for (int reg = 0; reg < 4; reg++) {
                float hv = fmaxf(c1t[nt][reg] + bn1v[nt], 0.f);
                h1T[wslot][(quad * 4 + reg) * 72 + n] = (ushort)bf16round(hv);
            }
        }
        __builtin_amdgcn_wave_barrier();

        // ---- layer 2: h1 @ Wn2 + bn2; h_new = h + . ----
        short8 a20 = *(const short8*)&h1T[wslot][l16 * 72 + quad * 8];
        short8 a21 = *(const short8*)&h1T[wslot][l16 * 72 + 32 + quad * 8];
        f32x4 hnewT[4];
        #pragma unroll
        for (int nt = 0; nt < 4; nt++) {
            f32x4 a = __builtin_amdgcn_mfma_f32_16x16x32_bf16(a20, wn2f[0][nt], z4, 0, 0, 0);
            f32x4 c = __builtin_amdgcn_mfma_f32_16x16x32_bf16(a21, wn2f[1][nt], a, 0, 0, 0);
            int n = nt * 16 + l16;
            #pragma unroll
            for (int reg = 0; reg < 4; reg++) {
                int node = n0 + quad * 4 + reg;
                int nc = min(node, N - 1);
                float hnew = h[(size_t)nc * 64 + n] + c[reg] + bn2v[nt];
                hnewT[nt][reg] = hnew;
                if (node < N) out[(size_t)node * 64 + n] = hnew;
            }
        }

        // ---- vel mlp ----
        __builtin_amdgcn_wave_barrier();
        #pragma unroll
        for (int nt = 0; nt < 4; nt++) {
            int n = nt * 16 + l16;
            #pragma unroll
            for (int reg = 0; reg < 4; reg++)
                h1T[wslot][(quad * 4 + reg) * 72 + n] = (ushort)bf16round(hnewT[nt][reg]);
        }
        __builtin_amdgcn_wave_barrier();
        short8 a30 = *(const short8*)&h1T[wslot][l16 * 72 + quad * 8];
        short8 a31 = *(const short8*)&h1T[wslot][l16 * 72 + 32 + quad * 8];
        float ps[4] = {0.f, 0.f, 0.f, 0.f};
        #pragma unroll
        for (int nt = 0; nt < 4; nt++) {
            f32x4 a = __builtin_amdgcn_mfma_f32_16x16x32_bf16(a30, wv1f[0][nt], z4, 0, 0, 0);
            f32x4 c = __builtin_amdgcn_mfma_f32_16x16x32_bf16(a31, wv1f[1][nt], a, 0, 0, 0);
            #pragma unroll
            for (int reg = 0; reg < 4; reg++)
                ps[reg] += fmaxf(c[reg] + bv1v[nt], 0.f) * wv2v[nt];
        }
        #pragma unroll
        for (int reg = 0; reg < 4; reg++) {
            ps[reg] += __shfl_xor(ps[reg], 1, 64);
            ps[reg] += __shfl_xor(ps[reg], 2, 64);
            ps[reg] += __shfl_xor(ps[reg], 4, 64);
            ps[reg] += __shfl_xor(ps[reg], 8, 64);
        }
        __builtin_amdgcn_wave_barrier();
        if (l16 == 0) {
            f32x4 pv = {ps[0] + bv2s, ps[1] + bv2s, ps[2] + bv2s, ps[3] + bv2s};
            *(f32x4*)&scT[wslot][quad * 4] = pv;
        }
        __builtin_amdgcn_wave_barrier();

        // ---- x_new / v_new ----
        if (lane < 48) {
            int nd = lane / 3, comp = lane - nd * 3;
            int node = n0 + nd;
            if (node < N) {
                float scale = scT[wslot][nd];
                float f = segF[(size_t)node * 12 + comp] * irT[wslot][nd];
                float v = scale * Z[(size_t)node * 12 + 3 + comp] + f;
                float x = Z[(size_t)node * 12 + comp] + v;
                out[OX + (size_t)node * 3 + comp] = x;
                out[OV + (size_t)node * 3 + comp] = v;
            }
        }
        __builtin_amdgcn_wave_barrier();
    }
}

extern "C" void kernel_launch(void* const* d_in, const int* in_sizes, int n_in,
                              void* d_out, int out_size, void* d_ws, size_t ws_size,
                              hipStream_t stream) {
    const float* h   = (const float*)d_in[0];
    const float* Z   = (const float*)d_in[1];
    const int*   row = (const int*)d_in[2];
    const int*   col = (const int*)d_in[3];
    const float* We1 = (const float*)d_in[4];
    const float* be1 = (const float*)d_in[5];
    const float* We2 = (const float*)d_in[6];
    const float* be2 = (const float*)d_in[7];
    const float* Wn1 = (const float*)d_in[8];
    const float* bn1 = (const float*)d_in[9];
    const float* Wn2 = (const float*)d_in[10];
    const float* bn2 = (const float*)d_in[11];
    const float* Wc1 = (const float*)d_in[12];
    const float* bc1 = (const float*)d_in[13];
    const float* Wc2 = (const float*)d_in[14];
    const float* Wv1 = (const float*)d_in[15];
    const float* bv1 = (const float*)d_in[16];
    const float* Wv2 = (const float*)d_in[17];
    const float* bv2 = (const float*)d_in[18];

    int N = in_sizes[0] / 64;
    int E = in_sizes[2];
    int nblk = (N + 1023) / 1024;

    // workspace layout; zeroed region first (cnt + fp32 accumulators)
    char* ws = (char*)d_ws;
    size_t o = 0;
    int* cntR    = (int*)(ws + o); o += (size_t)N * 4;
    int* cntC    = (int*)(ws + o); o += (size_t)N * 4;
    float* aggF  = (float*)(ws + o); o += (size_t)N * 64 * 4;   // 12.8 MB
    float* segF  = (float*)(ws + o); o += (size_t)N * 12 * 4;   //  2.4 MB
    size_t zero_bytes = o;
    int* rowptr  = (int*)(ws + o); o += (size_t)(N + 1) * 4;
    int* colptr  = (int*)(ws + o); o += (size_t)(N + 1) * 4;
    int* bsumR   = (int*)(ws + o); o += (size_t)nblk * 4;
    int* bsumC   = (int*)(ws + o); o += (size_t)nblk * 4;
    int* rank_r  = (int*)(ws + o); o += (size_t)E * 4;
    int* rank_c  = (int*)(ws + o); o += (size_t)E * 4;
    o = (o + 15) & ~(size_t)15;
    uint2* rs_rc = (uint2*)(ws + o); o += (size_t)E * 8;        // 6.4 MB
    int* rs_pc   = (int*)(ws + o); o += (size_t)E * 4;          // 3.2 MB
    ushort* Xrow = (ushort*)(ws + o); o += (size_t)N * 64 * 2;
    ushort* Xcol = (ushort*)(ws + o); o += (size_t)N * 64 * 2;
    ushort* hbf  = (ushort*)(ws + o); o += (size_t)N * 64 * 2;
    ushort* othersB = (ushort*)(ws + o); o += (size_t)N * 64 * 2;
    ushort* ef_col = (ushort*)(ws + o); o += (size_t)E * 64 * 2;  // 102.4 MB
    float* out = (float*)d_out;

    hipMemsetAsync(d_ws, 0, zero_bytes, stream);
    hist_rank<<<1024, 256, 0, stream>>>(row, col, cntR, cntC, rank_r, rank_c, E);
    scan_block<<<dim3(nblk, 2), 1024, 0, stream>>>(cntR, cntC, rowptr, colptr,
                                                   bsumR, bsumC, N);
    scan_totals<<<1, 64, 0, stream>>>(bsumR, bsumC, rowptr, colptr, nblk, N);
    scan_add<<<dim3(nblk, 2), 1024, 0, stream>>>(rowptr, colptr, bsumR, bsumC, N);
    perm_build<<<1024, 256, 0, stream>>>(row, col, rowptr, colptr,
                                         rank_r, rank_c, rs_rc, rs_pc, E);
    precompute_xrowcol<<<512, 256, 0, stream>>>(h, We1, be1, Xrow, Xcol, hbf, N);
    edge_kernel<<<1024, 256, 0, stream>>>(Z, rs_rc, rs_pc, Xrow, Xcol,
                                          We1, We2, be2, Wc1, bc1, Wc2,
                                          ef_col, aggF, segF, E);
    reduce_kernel<<<2048, 256, 0, stream>>>(colptr, ef_col, othersB, N);
    mlp_kernel<<<200, 256, 0, stream>>>(h, Z, hbf, aggF, othersB, segF, rowptr,
                                        Wn1, bn1, Wn2, bn2, Wv1, bv1, Wv2, bv2,
                                        out, N);
}